// Round 2
// baseline (705.819 us; speedup 1.0000x reference)
//
#include <hip/hip_runtime.h>
#include <hip/hip_bf16.h>

#define BB 4
#define NN 4096
#define KK 16
#define DP 64
#define DM 128
#define DMP 132   // padded LDS row stride (floats); 528 B, 16B-aligned
#define EPSF 1e-8f
#define OUT0N ((size_t)BB * NN * DP)   // elements in out0

typedef unsigned short u16t;
typedef __attribute__((ext_vector_type(8))) short s8v;   // 8 bf16 (4 VGPRs)
typedef __attribute__((ext_vector_type(4))) float f4v;   // MFMA accumulator

__device__ int g_flag;   // 0 = buffers are fp32, 1 = buffers are bf16

__device__ __forceinline__ float u2f(u16t u) {
    unsigned int x = ((unsigned int)u) << 16;
    return __uint_as_float(x);
}
__device__ __forceinline__ u16t f2u(float v) {
    __hip_bfloat16 h = __float2bfloat16(v);
    return *(u16t*)&h;
}

// ---------------- dtype-abstracted IO -----------------
template<int DT> struct IO;
template<> struct IO<0> {   // fp32
    static __device__ __forceinline__ float ld(const void* p, size_t i) { return ((const float*)p)[i]; }
    static __device__ __forceinline__ void ld4(const void* p, size_t i, float o[4]) {
        float4 v = *(const float4*)((const float*)p + i);
        o[0] = v.x; o[1] = v.y; o[2] = v.z; o[3] = v.w;
    }
    static __device__ __forceinline__ void st(void* p, size_t i, float v) { ((float*)p)[i] = v; }
};
template<> struct IO<1> {   // bf16
    static __device__ __forceinline__ float ld(const void* p, size_t i) { return u2f(((const u16t*)p)[i]); }
    static __device__ __forceinline__ void ld4(const void* p, size_t i, float o[4]) {
        ushort4 v = *(const ushort4*)((const u16t*)p + i);
        o[0] = u2f(v.x); o[1] = u2f(v.y); o[2] = u2f(v.z); o[3] = u2f(v.w);
    }
    static __device__ __forceinline__ void st(void* p, size_t i, float v) { ((u16t*)p)[i] = f2u(v); }
};

// ---------------- dtype detector ----------------------
__global__ __launch_bounds__(64) void detect_kernel(const void* feat) {
    const int tid = threadIdx.x;
    float x = u2f(((const u16t*)feat)[2 * tid]);
    float a = fabsf(x);
    bool sane = (x == 0.0f) || (a > 1e-4f && a < 50.0f);   // NaN/inf -> false
    unsigned long long m = __ballot(sane);
    if (tid == 0) g_flag = (__popcll(m) >= 32) ? 1 : 0;
}

// ---------------- kernel A (fallback): qkv, 1 pt/block
struct QkvSmem { float sf[DP]; float sx[DM]; };

template<int DT>
__device__ __forceinline__ void qkv_body(QkvSmem& s,
    const void* feat, const void* fc1_w, const void* fc1_b,
    const void* wq, const void* wk, const void* wv,
    float* __restrict__ qbuf, float* __restrict__ kbuf, float* __restrict__ vbuf)
{
    const int bn = blockIdx.x;
    const int tid = threadIdx.x;
    if (tid < DP) s.sf[tid] = IO<DT>::ld(feat, (size_t)bn * DP + tid);
    __syncthreads();
    float x = IO<DT>::ld(fc1_b, tid);
#pragma unroll 4
    for (int i = 0; i < DP; i++) x = fmaf(s.sf[i], IO<DT>::ld(fc1_w, i * DM + tid), x);
    s.sx[tid] = x;
    __syncthreads();
    float q = 0.f, k = 0.f, v = 0.f;
    for (int i0 = 0; i0 < DM; i0 += 4) {
        float4 xv = *(const float4*)&s.sx[i0];
        const float xs[4] = { xv.x, xv.y, xv.z, xv.w };
#pragma unroll
        for (int j = 0; j < 4; j++) {
            q = fmaf(xs[j], IO<DT>::ld(wq, (i0 + j) * DM + tid), q);
            k = fmaf(xs[j], IO<DT>::ld(wk, (i0 + j) * DM + tid), k);
            v = fmaf(xs[j], IO<DT>::ld(wv, (i0 + j) * DM + tid), v);
        }
    }
    qbuf[(size_t)bn * DM + tid] = q;
    kbuf[(size_t)bn * DM + tid] = k;
    vbuf[(size_t)bn * DM + tid] = v;
}

__global__ __launch_bounds__(128) void qkv_kernel(
    const void* feat, const void* fc1_w, const void* fc1_b,
    const void* wq, const void* wk, const void* wv,
    float* qbuf, float* kbuf, float* vbuf)
{
    __shared__ __align__(16) QkvSmem s;
    if (g_flag) qkv_body<1>(s, feat, fc1_w, fc1_b, wq, wk, wv, qbuf, kbuf, vbuf);
    else        qkv_body<0>(s, feat, fc1_w, fc1_b, wq, wk, wv, qbuf, kbuf, vbuf);
}

// ---------------- kernel A': qkv, 16 pts/block -------
// Weight traffic amortized 16x: each weight element read once per block.
// 256 threads: tid&127 = output col, tid>>7 = point-half (8 pts each).
struct Qkv16Smem { float sf[16][DP]; float sx[16][DMP]; };

template<int DT>
__device__ __forceinline__ void qkv16_body(Qkv16Smem& s,
    const void* feat, const void* fc1_w, const void* fc1_b,
    const void* wq, const void* wk, const void* wv,
    float* __restrict__ qbuf, float* __restrict__ kbuf, float* __restrict__ vbuf)
{
    const int pnt0 = blockIdx.x << 4;
    const int tid = threadIdx.x;
    {   // stage 16x64 features, one float4 per thread
        const int r = tid >> 4, c4 = (tid & 15) << 2;
        float o[4];
        IO<DT>::ld4(feat, (size_t)(pnt0 + r) * DP + c4, o);
        s.sf[r][c4 + 0] = o[0]; s.sf[r][c4 + 1] = o[1];
        s.sf[r][c4 + 2] = o[2]; s.sf[r][c4 + 3] = o[3];
    }
    __syncthreads();
    const int c = tid & 127, h = tid >> 7;
    {   // X = feat @ fc1_w + fc1_b, 8 points per thread
        float acc[8];
        const float fb = IO<DT>::ld(fc1_b, c);
#pragma unroll
        for (int pp = 0; pp < 8; pp++) acc[pp] = fb;
        for (int i = 0; i < DP; i++) {
            const float w = IO<DT>::ld(fc1_w, (size_t)i * DM + c);
#pragma unroll
            for (int pp = 0; pp < 8; pp++) acc[pp] = fmaf(s.sf[h * 8 + pp][i], w, acc[pp]);
        }
#pragma unroll
        for (int pp = 0; pp < 8; pp++) s.sx[h * 8 + pp][c] = acc[pp];
    }
    __syncthreads();
    {   // q/k/v = X @ W, 8 points per thread, weights loaded once
        float aq[8], ak[8], av[8];
#pragma unroll
        for (int pp = 0; pp < 8; pp++) { aq[pp] = 0.f; ak[pp] = 0.f; av[pp] = 0.f; }
        for (int i0 = 0; i0 < DM; i0 += 4) {
            float x4[8][4];
#pragma unroll
            for (int pp = 0; pp < 8; pp++) {
                const float4 xv = *(const float4*)&s.sx[h * 8 + pp][i0];
                x4[pp][0] = xv.x; x4[pp][1] = xv.y; x4[pp][2] = xv.z; x4[pp][3] = xv.w;
            }
#pragma unroll
            for (int j = 0; j < 4; j++) {
                const float wqv = IO<DT>::ld(wq, (size_t)(i0 + j) * DM + c);
                const float wkv = IO<DT>::ld(wk, (size_t)(i0 + j) * DM + c);
                const float wvv = IO<DT>::ld(wv, (size_t)(i0 + j) * DM + c);
#pragma unroll
                for (int pp = 0; pp < 8; pp++) {
                    aq[pp] = fmaf(x4[pp][j], wqv, aq[pp]);
                    ak[pp] = fmaf(x4[pp][j], wkv, ak[pp]);
                    av[pp] = fmaf(x4[pp][j], wvv, av[pp]);
                }
            }
        }
#pragma unroll
        for (int pp = 0; pp < 8; pp++) {
            const size_t row = (size_t)(pnt0 + h * 8 + pp) * DM + c;
            qbuf[row] = aq[pp]; kbuf[row] = ak[pp]; vbuf[row] = av[pp];
        }
    }
}

__global__ __launch_bounds__(256) void qkv16_kernel(
    const void* feat, const void* fc1_w, const void* fc1_b,
    const void* wq, const void* wk, const void* wv,
    float* qbuf, float* kbuf, float* vbuf)
{
    __shared__ __align__(16) Qkv16Smem s;
    if (g_flag) qkv16_body<1>(s, feat, fc1_w, fc1_b, wq, wk, wv, qbuf, kbuf, vbuf);
    else        qkv16_body<0>(s, feat, fc1_w, fc1_b, wq, wk, wv, qbuf, kbuf, vbuf);
}

// ---------------- kernel B: knn (wave-per-query) -----
template<int DT>
__device__ __forceinline__ void knn_body(float4* __restrict__ sc,
    const void* xyz, int* dst, int dstride, void* dout, int in_out)
{
    if (in_out) {
        if (DT) { dst = (int*)((u16t*)dout + OUT0N); dstride = (KK * DM) / 2; }
        else    { dst = (int*)((float*)dout + OUT0N); dstride = KK * DM; }
    }
    const int b = blockIdx.x >> 9;             // 512 blocks per batch
    const int tid = threadIdx.x;
    for (int j = tid; j < NN; j += 512) {
        float x = IO<DT>::ld(xyz, ((size_t)b * NN + j) * 3 + 0);
        float y = IO<DT>::ld(xyz, ((size_t)b * NN + j) * 3 + 1);
        float z = IO<DT>::ld(xyz, ((size_t)b * NN + j) * 3 + 2);
        float sq = __fadd_rn(__fadd_rn(__fmul_rn(x, x), __fmul_rn(y, y)), __fmul_rn(z, z));
        sc[j] = make_float4(x, y, z, sq);
    }
    __syncthreads();
    const int lane = tid & 63;
    const int wave = tid >> 6;
    const int r = ((blockIdx.x & 511) << 3) + wave;   // query row within batch
    const float4 qc = sc[r];                          // wave-uniform broadcast

    float d[KK];
    int id[KK];
#pragma unroll
    for (int t = 0; t < KK; t++) { d[t] = 3.4e38f; id[t] = 0x7fffffff; }

    for (int j = lane; j < NN; j += 64) {
        const float4 c = sc[j];
        const float dot = __fadd_rn(__fadd_rn(__fmul_rn(qc.x, c.x), __fmul_rn(qc.y, c.y)),
                                    __fmul_rn(qc.z, c.z));
        const float dist = __fsub_rn(__fadd_rn(qc.w, c.w), __fmul_rn(2.0f, dot));
        if (dist < d[KK - 1]) {
            float cd = dist; int ci = j;
#pragma unroll
            for (int t = 0; t < KK; t++) {
                const bool sw = (cd < d[t]);          // strict: stable ties
                const float od = d[t]; const int oi = id[t];
                d[t]  = sw ? cd : d[t];
                id[t] = sw ? ci : id[t];
                cd = sw ? od : cd;
                ci = sw ? oi : ci;
            }
        }
    }

    // wave merge: 16x pop-min over 64 sorted lists
    const size_t base = (size_t)(b * NN + r) * (size_t)dstride;
#pragma unroll
    for (int t = 0; t < KK; t++) {
        float bd = d[0]; int bi = id[0];
#pragma unroll
        for (int off = 32; off >= 1; off >>= 1) {
            const float od = __shfl_xor(bd, off, 64);
            const int   oi = __shfl_xor(bi, off, 64);
            if (od < bd || (od == bd && oi < bi)) { bd = od; bi = oi; }
        }
        const bool win = (d[0] == bd) && (id[0] == bi);   // unique (dist,idx)
        if (win) {
#pragma unroll
            for (int u = 0; u < KK - 1; u++) { d[u] = d[u + 1]; id[u] = id[u + 1]; }
            d[KK - 1] = 3.4e38f; id[KK - 1] = 0x7fffffff;
        }
        if (lane == t) dst[base + t] = bi;
    }
}

__global__ __launch_bounds__(512) void knn_kernel(
    const void* xyz, int* dst, int dstride, void* dout, int in_out)
{
    __shared__ __align__(16) float4 sc[NN];   // 64 KB
    if (g_flag) knn_body<1>(sc, xyz, dst, dstride, dout, in_out);
    else        knn_body<0>(sc, xyz, dst, dstride, dout, in_out);
}

// ---------------- GEMM tile helper (fallback path) ----
template<int DT>
__device__ __forceinline__ void gemm_tile(const float* __restrict__ IN,
                                          const void* __restrict__ W, int woff,
                                          int kg, int f0, float acc[4][4])
{
#pragma unroll
    for (int a = 0; a < 4; a++)
#pragma unroll
        for (int c = 0; c < 4; c++) acc[a][c] = 0.f;
    for (int i0 = 0; i0 < DM; i0 += 4) {
        float w[4][4];
#pragma unroll
        for (int j = 0; j < 4; j++) IO<DT>::ld4(W, (size_t)woff + (i0 + j) * DM + f0, w[j]);
#pragma unroll
        for (int kk = 0; kk < 4; kk++) {
            float4 x4 = *(const float4*)(IN + (kg * 4 + kk) * DMP + i0);
            const float xs[4] = { x4.x, x4.y, x4.z, x4.w };
#pragma unroll
            for (int ff = 0; ff < 4; ff++)
#pragma unroll
                for (int j = 0; j < 4; j++)
                    acc[kk][ff] = fmaf(xs[j], w[j][ff], acc[kk][ff]);
        }
    }
}

// =====================================================
// Weight prep: pack 4 DMxDM matrices (sim_w[1:], d2_w,
// g1_w, g2_w) into MFMA B-fragment order, split fp32 ->
// hi/lo bf16.  Layout per matrix (16384 shorts hi, then
// 16384 shorts lo): frag offset ((tile*4+ks)*64+lane)*8,
// element j = W[ks*32+(lane>>4)*8+j][tile*16+(lane&15)].
// =====================================================
template<int DT>
__device__ __forceinline__ void wprep_body(const void* sim_w, const void* d2_w,
                                           const void* g1_w, const void* g2_w,
                                           u16t* __restrict__ wprep)
{
    const int m  = blockIdx.x >> 3;    // matrix 0..3
    const int t  = blockIdx.x & 7;     // col tile 0..7
    const int ks = threadIdx.x >> 6;   // k-step 0..3
    const int lane = threadIdx.x & 63;
    const void* src = (m == 0) ? sim_w : (m == 1) ? d2_w : (m == 2) ? g1_w : g2_w;
    const int srcoff = (m == 0) ? DM : 0;   // sim_w: skip row 0 (handled in epilogue)
    u16t* hi = wprep + (size_t)m * 32768;
    u16t* lo = hi + 16384;
    const int c  = t * 16 + (lane & 15);
    const int k0 = ks * 32 + ((lane >> 4) << 3);
    s8v vh, vl;
#pragma unroll
    for (int j = 0; j < 8; j++) {
        const float x = IO<DT>::ld(src, (size_t)srcoff + (size_t)(k0 + j) * DM + c);
        const u16t h = f2u(x);
        vh[j] = (short)h;
        vl[j] = (short)f2u(x - u2f(h));
    }
    const size_t off = ((size_t)(t * 4 + ks) * 64 + lane) * 8;
    *(s8v*)(hi + off) = vh;
    *(s8v*)(lo + off) = vl;
}

__global__ __launch_bounds__(256) void wprep_kernel(
    const void* sim_w, const void* d2_w, const void* g1_w, const void* g2_w,
    u16t* wprep)
{
    if (g_flag) wprep_body<1>(sim_w, d2_w, g1_w, g2_w, wprep);
    else        wprep_body<0>(sim_w, d2_w, g1_w, g2_w, wprep);
}

// =====================================================
// Split-fp32 MFMA 64x128 @ 128x128 tile (4 points).
// 8 waves: wave w -> M-tile (w&3), col-half (w>>2).
// Waves sharing a col-half load identical B fragments
// (L1 dedup) -> L2 weight traffic /4 vs 1-pt blocks.
// Layouts (v_mfma_f32_16x16x32_bf16, m89-verified C/D):
//   A: row = lane&15, k = ks*32 + (lane>>4)*8 + j
//   B: col = lane&15, k = ks*32 + (lane>>4)*8 + j
//   D: col = lane&15, row = (lane>>4)*4 + r
// EPI: 0 = +bias, 1 = relu(+bias), 2 = +sim*w0 + bias
// =====================================================
template<int DT, int EPI>
__device__ __forceinline__ void mfma_gemm64(const float* __restrict__ IN,
                                            float* __restrict__ OUT,
                                            const u16t* __restrict__ wmat,
                                            const void* bias, const void* w0,
                                            const float* __restrict__ ssim)
{
    const int tid  = threadIdx.x;
    const int lane = tid & 63;
    const int wid  = tid >> 6;
    const int mt   = wid & 3;      // M tile = point
    const int ch   = wid >> 2;     // col half
    const u16t* whi = wmat;
    const u16t* wlo = wmat + 16384;
    f4v acc[4] = { {0.f,0.f,0.f,0.f}, {0.f,0.f,0.f,0.f}, {0.f,0.f,0.f,0.f}, {0.f,0.f,0.f,0.f} };
    const float* ain = IN + (size_t)(mt * 16 + (lane & 15)) * DMP + ((lane >> 4) << 3);
#pragma unroll
    for (int ks = 0; ks < 4; ks++) {
        const float4 x0 = *(const float4*)(ain + ks * 32);
        const float4 x1 = *(const float4*)(ain + ks * 32 + 4);
        const float xs[8] = { x0.x, x0.y, x0.z, x0.w, x1.x, x1.y, x1.z, x1.w };
        s8v ahi, alo;
#pragma unroll
        for (int j = 0; j < 8; j++) {
            const u16t h = f2u(xs[j]);
            ahi[j] = (short)h;
            alo[j] = (short)f2u(xs[j] - u2f(h));
        }
#pragma unroll
        for (int t = 0; t < 4; t++) {
            const size_t off = ((size_t)((ch * 4 + t) * 4 + ks) * 64 + lane) * 8;
            const s8v bhi = *(const s8v*)(whi + off);
            const s8v blo = *(const s8v*)(wlo + off);
            acc[t] = __builtin_amdgcn_mfma_f32_16x16x32_bf16(ahi, bhi, acc[t], 0, 0, 0);
            acc[t] = __builtin_amdgcn_mfma_f32_16x16x32_bf16(ahi, blo, acc[t], 0, 0, 0);
            acc[t] = __builtin_amdgcn_mfma_f32_16x16x32_bf16(alo, bhi, acc[t], 0, 0, 0);
        }
    }
    const int r0 = (lane >> 4) * 4;
#pragma unroll
    for (int t = 0; t < 4; t++) {
        const int col = (ch * 4 + t) * 16 + (lane & 15);
        const float bv = IO<DT>::ld(bias, col);
        float w0v = 0.f;
        if constexpr (EPI == 2) w0v = IO<DT>::ld(w0, col);
#pragma unroll
        for (int r = 0; r < 4; r++) {
            const int row = mt * 16 + r0 + r;
            float v = acc[t][r] + bv;
            if constexpr (EPI == 2) v = fmaf(ssim[row], w0v, v);
            if constexpr (EPI == 1) v = fmaxf(v, 0.f);
            OUT[(size_t)row * DMP + col] = v;
        }
    }
}

// ---------------- kernel C': MFMA attn, 4 pts/block --
// 512 threads, 8 waves, ~107 KB LDS, 1 block/CU.
// Row index within tiles: point*16 + neighbor (0..63).
struct AttnSmem4 {
    float KP[64 * DMP];   // K gather, later PE
    float T0[64 * DMP];
    float T1[64 * DMP];
    float s_q[4 * DM], sres[4 * DM];
    float srp[64][3];
    float ssim[64], skn[64], sdot[64];
    float sqn[4];
    int sidx[64];
};

template<int DT>
__device__ __forceinline__ void attn4_body(AttnSmem4& s,
    const void* xyz, const void* feat,
    const void* fc2_w, const void* fc2_b,
    const void* d1_w, const void* d1_b, const void* d2_b,
    const void* g1_b, const void* g2_b,
    const void* sim_w, const void* sim_b,
    const float* __restrict__ qbuf, const float* __restrict__ kbuf,
    const float* __restrict__ vbuf,
    const int* __restrict__ knn, const u16t* __restrict__ wprep, void* dout)
{
    void* out0 = dout;
    void* out1 = DT ? (void*)((u16t*)dout + OUT0N) : (void*)((float*)dout + OUT0N);
    const int pnt0 = blockIdx.x << 2;   // first point (global, incl batch)
    const int b = pnt0 >> 12;
    const int tid = threadIdx.x;

    if (tid < 64) {
        int sv = knn[(size_t)(pnt0 + (tid >> 4)) * KK + (tid & 15)];
        sv = (sv < 0) ? 0 : (sv > NN - 1 ? NN - 1 : sv);
        s.sidx[tid] = sv;
    }
    __syncthreads();

    // gather q, K, rel_pos
    {
        const int p = tid >> 7, ff = tid & 127;
        s.s_q[tid] = qbuf[(size_t)(pnt0 + p) * DM + ff];
#pragma unroll
        for (int k = 0; k < KK; k++) {
            const int row = p * 16 + k;
            const int grow = (b << 12) + s.sidx[row];
            s.KP[row * DMP + ff] = kbuf[(size_t)grow * DM + ff];
        }
    }
    if (tid < 64) {
        const int grow = (b << 12) + s.sidx[tid];
        const int p = tid >> 4;
#pragma unroll
        for (int c = 0; c < 3; c++)
            s.srp[tid][c] = IO<DT>::ld(xyz, (size_t)(pnt0 + p) * 3 + c)
                          - IO<DT>::ld(xyz, (size_t)grow * 3 + c);
    }
    __syncthreads();

    // norms + q.k dots: 8 lanes per (point,neighbor) row
    {
        const int j = tid >> 3, g = tid & 7, p = j >> 4;
        float sk = 0.f, sd = 0.f, qq = 0.f;
#pragma unroll
        for (int i = 0; i < 16; i++) {
            const int ff = g * 16 + i;
            const float kv = s.KP[j * DMP + ff];
            const float qv = s.s_q[p * DM + ff];
            sk = fmaf(kv, kv, sk);
            sd = fmaf(qv, kv, sd);
            qq = fmaf(qv, qv, qq);
        }
#pragma unroll
        for (int off = 1; off <= 4; off <<= 1) {
            sk += __shfl_xor(sk, off, 64);
            sd += __shfl_xor(sd, off, 64);
            qq += __shfl_xor(qq, off, 64);
        }
        if (g == 0) {
            s.skn[j] = fmaxf(sqrtf(sk), EPSF);
            s.sdot[j] = sd;
            if ((j & 15) == 0) s.sqn[p] = fmaxf(sqrtf(qq), EPSF);
        }
    }
    __syncthreads();

    if (tid < 64) s.ssim[tid] = s.sdot[tid] / (s.sqn[tid >> 4] * s.skn[tid]);
    // T0 = q - K
    {
        const int p = tid >> 7, ff = tid & 127;
#pragma unroll
        for (int k = 0; k < KK; k++) {
            const int row = p * 16 + k;
            s.T0[row * DMP + ff] = s.s_q[p * DM + ff] - s.KP[row * DMP + ff];
        }
    }
    __syncthreads();

    // T1 = rel_qk = [sim, q-k] @ sim_w + sim_b
    mfma_gemm64<DT, 2>(s.T0, s.T1, wprep + 0 * 32768, sim_b, sim_w, s.ssim);
    __syncthreads();

    // T0 = h = relu(rel_pos @ d1_w + d1_b)
    {
        const int p = tid >> 7, ff = tid & 127;
        const float w0 = IO<DT>::ld(d1_w, 0 * DM + ff), w1 = IO<DT>::ld(d1_w, 1 * DM + ff),
                    w2 = IO<DT>::ld(d1_w, 2 * DM + ff);
        const float hb = IO<DT>::ld(d1_b, ff);
#pragma unroll
        for (int k = 0; k < KK; k++) {
            const int row = p * 16 + k;
            const float h = fmaf(s.srp[row][2], w2,
                            fmaf(s.srp[row][1], w1, fmaf(s.srp[row][0], w0, hb)));
            s.T0[row * DMP + ff] = fmaxf(h, 0.f);
        }
    }
    __syncthreads();

    // KP = pos_enc = h @ d2_w + d2_b   (K is dead, alias)
    mfma_gemm64<DT, 0>(s.T0, s.KP, wprep + 1 * 32768, d2_b, nullptr, nullptr);
    __syncthreads();

    // T0 = rel_qk + pos_enc
    {
        const int p = tid >> 7, ff = tid & 127;
#pragma unroll
        for (int k = 0; k < KK; k++) {
            const int row = p * 16 + k;
            s.T0[row * DMP + ff] = s.T1[row * DMP + ff] + s.KP[row * DMP + ff];
        }
    }
    __syncthreads();

    // T1 = relu(T0 @ g1_w + g1_b)
    mfma_gemm64<DT, 1>(s.T0, s.T1, wprep + 2 * 32768, g1_b, nullptr, nullptr);
    __syncthreads();

    // T0 = T1 @ g2_w + g2_b
    mfma_gemm64<DT, 0>(s.T1, s.T0, wprep + 3 * 32768, g2_b, nullptr, nullptr);
    __syncthreads();

    // softmax over K + einsum (V re-gathered, PE from KP)
    {
        const int p = tid >> 7, ff = tid & 127;
        const float sq128 = 11.31370849898476f;
        float tv[KK];
        float mx = -3.4e38f;
#pragma unroll
        for (int k = 0; k < KK; k++) {
            tv[k] = s.T0[(p * 16 + k) * DMP + ff] / sq128;
            mx = fmaxf(mx, tv[k]);
        }
        float ssum = 0.f;
#pragma unroll
        for (int k = 0; k < KK; k++) { tv[k] = expf(tv[k] - mx); ssum += tv[k]; }
        float rf = 0.f;
#pragma unroll
        for (int k = 0; k < KK; k++) {
            const float a = tv[k] / ssum;
            IO<DT>::st(out1, ((size_t)(pnt0 + p) * KK + k) * DM + ff, a);
            const int row = p * 16 + k;
            const int grow = (b << 12) + s.sidx[row];
            rf = fmaf(a, vbuf[(size_t)grow * DM + ff] + s.KP[row * DMP + ff], rf);
        }
        s.sres[tid] = rf;
    }
    __syncthreads();

    // out0 = res @ fc2_w + fc2_b + features
    if (tid < 256) {
        const int p = tid >> 6, c = tid & 63;
        float o = 0.f;
        for (int i = 0; i < DM; i++) o = fmaf(s.sres[p * DM + i], IO<DT>::ld(fc2_w, (size_t)i * DP + c), o);
        o = o + IO<DT>::ld(fc2_b, c) + IO<DT>::ld(feat, (size_t)(pnt0 + p) * DP + c);
        IO<DT>::st(out0, (size_t)(pnt0 + p) * DP + c, o);
    }
}

__global__ __launch_bounds__(512) void attn4_kernel(
    const void* xyz, const void* feat,
    const void* fc2_w, const void* fc2_b,
    const void* d1_w, const void* d1_b, const void* d2_b,
    const void* g1_b, const void* g2_b,
    const void* sim_w, const void* sim_b,
    const float* qbuf, const float* kbuf, const float* vbuf,
    const int* knn, const u16t* wprep, void* dout)
{
    __shared__ __align__(16) AttnSmem4 s;
    if (g_flag)
        attn4_body<1>(s, xyz, feat, fc2_w, fc2_b, d1_w, d1_b, d2_b, g1_b, g2_b,
                      sim_w, sim_b, qbuf, kbuf, vbuf, knn, wprep, dout);
    else
        attn4_body<0>(s, xyz, feat, fc2_w, fc2_b, d1_w, d1_b, d2_b, g1_b, g2_b,
                      sim_w, sim_b, qbuf, kbuf, vbuf, knn, wprep, dout);
}

// ---------------- kernel C: attn (fallback paths) ----
template<bool FUSED> struct AttnSmem {
    float Kb[KK * DMP], Vb[KK * DMP], PE[KK * DMP], T0[KK * DMP], T1[KK * DMP];
    float s_q[DM], sres[DM];
    float SF[FUSED ? 17 * DP : 1];
    float X[FUSED ? 17 * DMP : 1];
    float srp[KK][3];
    float ssim[KK], skn[KK], sdot[KK];
    float sqn;
    int sidx[KK];
};

template<int DT, bool FUSED>
__device__ __forceinline__ void attn_body(AttnSmem<FUSED>& s,
    const void* xyz, const void* feat,
    const void* fc1_w, const void* fc1_b, const void* fc2_w, const void* fc2_b,
    const void* d1_w, const void* d1_b, const void* d2_w, const void* d2_b,
    const void* g1_w, const void* g1_b, const void* g2_w, const void* g2_b,
    const void* sim_w, const void* sim_b,
    const void* wq, const void* wk, const void* wv,
    const float* __restrict__ qbuf, const float* __restrict__ kbuf, const float* __restrict__ vbuf,
    const int* knn, int knn_stride, int knn_in_out, void* dout)
{
    void* out0 = dout;
    void* out1 = DT ? (void*)((u16t*)dout + OUT0N) : (void*)((float*)dout + OUT0N);
    if (knn_in_out) {
        if (DT) { knn = (const int*)((const u16t*)dout + OUT0N); knn_stride = (KK * DM) / 2; }
        else    { knn = (const int*)((const float*)dout + OUT0N); knn_stride = KK * DM; }
    }

    const int bn = blockIdx.x;
    const int b = bn >> 12;
    const int tid = threadIdx.x;
    const int f = tid;
    const int f0 = (tid & 31) * 4;
    const int kg = tid >> 5;

    if (tid < KK) {
        int sv = knn[(size_t)bn * knn_stride + tid];
        sv = (sv < 0) ? 0 : (sv > NN - 1 ? NN - 1 : sv);   // defensive, never OOB
        s.sidx[tid] = sv;
    }
    __syncthreads();

    if constexpr (FUSED) {
        for (int idx = tid; idx < 17 * DP; idx += 128) {
            const int r = idx >> 6, c = idx & 63;
            const int row = (r < KK) ? ((b << 12) + s.sidx[r]) : bn;
            s.SF[idx] = IO<DT>::ld(feat, (size_t)row * DP + c);
        }
        __syncthreads();
        float xacc[17];
        const float fb = IO<DT>::ld(fc1_b, tid);
#pragma unroll
        for (int r = 0; r < 17; r++) xacc[r] = fb;
        for (int i = 0; i < DP; i++) {
            const float w = IO<DT>::ld(fc1_w, i * DM + tid);
#pragma unroll
            for (int r = 0; r < 17; r++) xacc[r] = fmaf(s.SF[r * DP + i], w, xacc[r]);
        }
#pragma unroll
        for (int r = 0; r < 17; r++) s.X[r * DMP + tid] = xacc[r];
        __syncthreads();
        {
            float a2[4][4];
            gemm_tile<DT>(s.X, wk, 0, kg, f0, a2);
#pragma unroll
            for (int kk = 0; kk < 4; kk++)
                *(float4*)&s.Kb[(kg * 4 + kk) * DMP + f0] =
                    make_float4(a2[kk][0], a2[kk][1], a2[kk][2], a2[kk][3]);
            gemm_tile<DT>(s.X, wv, 0, kg, f0, a2);
#pragma unroll
            for (int kk = 0; kk < 4; kk++)
                *(float4*)&s.Vb[(kg * 4 + kk) * DMP + f0] =
                    make_float4(a2[kk][0], a2[kk][1], a2[kk][2], a2[kk][3]);
        }
        {
            float qv = 0.f;
            for (int i0 = 0; i0 < DM; i0 += 4) {
                float4 x4 = *(const float4*)&s.X[16 * DMP + i0];
                const float xs[4] = { x4.x, x4.y, x4.z, x4.w };
#pragma unroll
                for (int j = 0; j < 4; j++)
                    qv = fmaf(xs[j], IO<DT>::ld(wq, (i0 + j) * DM + tid), qv);
            }
            s.s_q[tid] = qv;
        }
    } else {
        s.s_q[f] = qbuf[(size_t)bn * DM + f];
#pragma unroll
        for (int k = 0; k < KK; k++) {
            const int row = (b << 12) + s.sidx[k];
            s.Kb[k * DMP + f] = kbuf[(size_t)row * DM + f];
            s.Vb[k * DMP + f] = vbuf[(size_t)row * DM + f];
        }
    }
    if (tid < KK) {
        const int row = (b << 12) + s.sidx[tid];
#pragma unroll
        for (int c = 0; c < 3; c++)
            s.srp[tid][c] = IO<DT>::ld(xyz, (size_t)bn * 3 + c) - IO<DT>::ld(xyz, (size_t)row * 3 + c);
    }
    __syncthreads();

    // norms + q.k dots
    if (tid < KK) {
        float sk = 0.f, sd = 0.f;
        for (int i = 0; i < DM; i++) {
            float v2 = s.Kb[tid * DMP + i];
            sk = fmaf(v2, v2, sk);
            sd = fmaf(s.s_q[i], v2, sd);
        }
        s.skn[tid] = fmaxf(sqrtf(sk), EPSF);
        s.sdot[tid] = sd;
    } else if (tid == KK) {
        float sqq = 0.f;
        for (int i = 0; i < DM; i++) { float v2 = s.s_q[i]; sqq = fmaf(v2, v2, sqq); }
        s.sqn = fmaxf(sqrtf(sqq), EPSF);
    }
    __syncthreads();
    if (tid < KK) s.ssim[tid] = s.sdot[tid] / (s.sqn * s.skn[tid]);
#pragma unroll
    for (int k = 0; k < KK; k++) s.T0[k * DMP + f] = s.s_q[f] - s.Kb[k * DMP + f];
    __syncthreads();

    float acc[4][4];

    // rel_qk = [sim, q-k] @ sim_w + sim_b  -> T1
    gemm_tile<DT>(s.T0, sim_w, DM, kg, f0, acc);
    {
        float w0f[4], sbf[4];
        IO<DT>::ld4(sim_w, f0, w0f);
        IO<DT>::ld4(sim_b, f0, sbf);
#pragma unroll
        for (int kk = 0; kk < 4; kk++) {
            float sm = s.ssim[kg * 4 + kk];
            float4 o;
            o.x = fmaf(sm, w0f[0], acc[kk][0]) + sbf[0];
            o.y = fmaf(sm, w0f[1], acc[kk][1]) + sbf[1];
            o.z = fmaf(sm, w0f[2], acc[kk][2]) + sbf[2];
            o.w = fmaf(sm, w0f[3], acc[kk][3]) + sbf[3];
            *(float4*)&s.T1[(kg * 4 + kk) * DMP + f0] = o;
        }
    }
    __syncthreads();

    // h = relu(rel_pos @ d1_w + d1_b) -> T0
    {
        float w0 = IO<DT>::ld(d1_w, 0 * DM + f), w1 = IO<DT>::ld(d1_w, 1 * DM + f),
              w2 = IO<DT>::ld(d1_w, 2 * DM + f);
        float hb = IO<DT>::ld(d1_b, f);
#pragma unroll
        for (int k = 0; k < KK; k++) {
            float h = fmaf(s.srp[k][2], w2, fmaf(s.srp[k][1], w1, fmaf(s.srp[k][0], w0, hb)));
            s.T0[k * DMP + f] = fmaxf(h, 0.f);
        }
    }
    __syncthreads();

    // pos_enc = h @ d2_w + d2_b -> PE
    gemm_tile<DT>(s.T0, d2_w, 0, kg, f0, acc);
    {
        float bf[4];
        IO<DT>::ld4(d2_b, f0, bf);
#pragma unroll
        for (int kk = 0; kk < 4; kk++)
            *(float4*)&s.PE[(kg * 4 + kk) * DMP + f0] =
                make_float4(acc[kk][0] + bf[0], acc[kk][1] + bf[1],
                            acc[kk][2] + bf[2], acc[kk][3] + bf[3]);
    }
    __syncthreads();

    // T0 = T1 + PE
#pragma unroll
    for (int kk = 0; kk < 4; kk++) {
        const int row = (kg * 4 + kk) * DMP + f0;
        float4 a4 = *(const float4*)&s.T1[row];
        float4 p4 = *(const float4*)&s.PE[row];
        *(float4*)&s.T0[row] = make_float4(a4.x + p4.x, a4.y + p4.y, a4.z + p4.z, a4.w + p4.w);
    }
    __syncthreads();

    // T1 = relu(T0 @ g1_w + g1_b)
    gemm_tile<DT>(s.T0, g1_w, 0, kg, f0, acc);
    {
        float bf[4];
        IO<DT>::ld4(g1_b, f0, bf);
#pragma unroll
        for (int kk = 0; kk < 4; kk++)
            *(float4*)&s.T1[(kg * 4 + kk) * DMP + f0] =
                make_float4(fmaxf(acc[kk][0] + bf[0], 0.f), fmaxf(acc[kk][1] + bf[1], 0.f),
                            fmaxf(acc[kk][2] + bf[2], 0.f), fmaxf(acc[kk][3] + bf[3], 0.f));
    }
    __syncthreads();

    // T0 = T1 @ g2_w + g2_b
    gemm_tile<DT>(s.T1, g2_w, 0, kg, f0, acc);
    {
        float bf[4];
        IO<DT>::ld4(g2_b, f0, bf);
#pragma unroll
        for (int kk = 0; kk < 4; kk++)
            *(float4*)&s.T0[(kg * 4 + kk) * DMP + f0] =
                make_float4(acc[kk][0] + bf[0], acc[kk][1] + bf[1],
                            acc[kk][2] + bf[2], acc[kk][3] + bf[3]);
    }
    __syncthreads();

    // softmax over K + einsum
    {
        const float sq128 = 11.31370849898476f;
        float tv[KK];
        float m = -3.4e38f;
#pragma unroll
        for (int k = 0; k < KK; k++) { tv[k] = s.T0[k * DMP + f] / sq128; m = fmaxf(m, tv[k]); }
        float ssum = 0.f;
#pragma unroll
        for (int k = 0; k < KK; k++) { tv[k] = expf(tv[k] - m); ssum += tv[k]; }
        float rf = 0.f;
#pragma unroll
        for (int k = 0; k < KK; k++) {
            float a = tv[k] / ssum;
            IO<DT>::st(out1, ((size_t)bn * KK + k) * DM + f, a);
            rf = fmaf(a, s.Vb[k * DMP + f] + s.PE[k * DMP + f], rf);
        }
        s.sres[f] = rf;
    }
    __syncthreads();

    // out0 = res @ fc2_w + fc2_b + features
    if (tid < DP) {
        float o = 0.f;
        for (int i = 0; i < DM; i++) o = fmaf(s.sres[i], IO<DT>::ld(fc2_w, i * DP + tid), o);
        o = o + IO<DT>::ld(fc2_b, tid) + IO<DT>::ld(feat, (size_t)bn * DP + tid);
        IO<DT>::st(out0, (size_t)bn * DP + tid, o);
    }
}

template<bool FUSED>
__global__ __launch_bounds__(128) void attn_kernel(
    const void* xyz, const void* feat,
    const void* fc1_w, const void* fc1_b, const void* fc2_w, const void* fc2_b,
    const void* d1_w, const void* d1_b, const void* d2_w, const void* d2_b,
    const void* g1_w, const void* g1_b, const void* g2_w, const void* g2_b,
    const void* sim_w, const void* sim_b,
    const void* wq, const void* wk, const void* wv,
    const float* qbuf, const float* kbuf, const float* vbuf,
    const int* knn, int knn_stride, int knn_in_out, void* dout)
{
    __shared__ __align__(16) AttnSmem<FUSED> s;
    if (g_flag)
        attn_body<1, FUSED>(s, xyz, feat, fc1_w, fc1_b, fc2_w, fc2_b, d1_w, d1_b, d2_w, d2_b,
                            g1_w, g1_b, g2_w, g2_b, sim_w, sim_b, wq, wk, wv,
                            qbuf, kbuf, vbuf, knn, knn_stride, knn_in_out, dout);
    else
        attn_body<0, FUSED>(s, xyz, feat, fc1_w, fc1_b, fc2_w, fc2_b, d1_w, d1_b, d2_w, d2_b,
                            g1_w, g1_b, g2_w, g2_b, sim_w, sim_b, wq, wk, wv,
                            qbuf, kbuf, vbuf, knn, knn_stride, knn_in_out, dout);
}

// ---------------------------------------------------------------- launch
extern "C" void kernel_launch(void* const* d_in, const int* in_sizes, int n_in,
                              void* d_out, int out_size, void* d_ws, size_t ws_size,
                              hipStream_t stream)
{
    const void* xyz   = d_in[0];
    const void* feat  = d_in[1];
    const void* fc1_w = d_in[2];
    const void* fc1_b = d_in[3];
    const void* fc2_w = d_in[4];
    const void* fc2_b = d_in[5];
    const void* d1_w  = d_in[6];
    const void* d1_b  = d_in[7];
    const void* d2_w  = d_in[8];
    const void* d2_b  = d_in[9];
    const void* g1_w  = d_in[10];
    const void* g1_b  = d_in[11];
    const void* g2_w  = d_in[12];
    const void* g2_b  = d_in[13];
    const void* wq_w  = d_in[14];
    const void* wk_w  = d_in[15];
    const void* wv_w  = d_in[16];
    const void* sim_w = d_in[17];
    const void* sim_b = d_in[18];

    detect_kernel<<<1, 64, 0, stream>>>(feat);

    const size_t need_qkv = (size_t)3 * BB * NN * DM * sizeof(float);
    const size_t need_knn = (size_t)BB * NN * KK * sizeof(int);
    const size_t need_wp  = (size_t)4 * 2 * 16384 * sizeof(u16t);   // 256 KB packed weights

    if (ws_size >= need_qkv + need_knn + need_wp && d_ws != nullptr) {
        float* qbuf  = (float*)d_ws;
        float* kbuf  = qbuf + (size_t)BB * NN * DM;
        float* vbuf  = kbuf + (size_t)BB * NN * DM;
        int*   knn   = (int*)(vbuf + (size_t)BB * NN * DM);
        u16t*  wprep = (u16t*)(knn + (size_t)BB * NN * KK);
        qkv16_kernel<<<(BB * NN) / 16, 256, 0, stream>>>(feat, fc1_w, fc1_b, wq_w, wk_w, wv_w,
                                                         qbuf, kbuf, vbuf);
        knn_kernel<<<BB * 512, 512, 0, stream>>>(xyz, knn, KK, d_out, 0);
        wprep_kernel<<<32, 256, 0, stream>>>(sim_w, d2_w, g1_w, g2_w, wprep);
        attn4_kernel<<<(BB * NN) / 4, 512, 0, stream>>>(
            xyz, feat, fc2_w, fc2_b, d1_w, d1_b, d2_b, g1_b, g2_b, sim_w, sim_b,
            qbuf, kbuf, vbuf, knn, wprep, d_out);
    } else if (ws_size >= need_qkv + need_knn && d_ws != nullptr) {
        float* qbuf = (float*)d_ws;
        float* kbuf = qbuf + (size_t)BB * NN * DM;
        float* vbuf = kbuf + (size_t)BB * NN * DM;
        int*   knn  = (int*)(vbuf + (size_t)BB * NN * DM);
        qkv_kernel<<<BB * NN, DM, 0, stream>>>(feat, fc1_w, fc1_b, wq_w, wk_w, wv_w, qbuf, kbuf, vbuf);
        knn_kernel<<<BB * 512, 512, 0, stream>>>(xyz, knn, KK, d_out, 0);
        attn_kernel<false><<<BB * NN, DM, 0, stream>>>(
            xyz, feat, fc1_w, fc1_b, fc2_w, fc2_b, d1_w, d1_b, d2_w, d2_b,
            g1_w, g1_b, g2_w, g2_b, sim_w, sim_b, wq_w, wk_w, wv_w,
            qbuf, kbuf, vbuf, knn, KK, 0, d_out);
    } else if (ws_size >= need_knn && d_ws != nullptr) {
        int* knn = (int*)d_ws;
        knn_kernel<<<BB * 512, 512, 0, stream>>>(xyz, knn, KK, d_out, 0);
        attn_kernel<true><<<BB * NN, DM, 0, stream>>>(
            xyz, feat, fc1_w, fc1_b, fc2_w, fc2_b, d1_w, d1_b, d2_w, d2_b,
            g1_w, g1_b, g2_w, g2_b, sim_w, sim_b, wq_w, wk_w, wv_w,
            nullptr, nullptr, nullptr, knn, KK, 0, d_out);
    } else {
        knn_kernel<<<BB * 512, 512, 0, stream>>>(xyz, nullptr, 0, d_out, 1);
        attn_kernel<true><<<BB * NN, DM, 0, stream>>>(
            xyz, feat, fc1_w, fc1_b, fc2_w, fc2_b, d1_w, d1_b, d2_w, d2_b,
            g1_w, g1_b, g2_w, g2_b, sim_w, sim_b, wq_w, wk_w, wv_w,
            nullptr, nullptr, nullptr, nullptr, 0, 1, d_out);
    }
}

// Round 3
// 645.007 us; speedup vs baseline: 1.0943x; 1.0943x over previous
//
#include <hip/hip_runtime.h>
#include <hip/hip_bf16.h>

#define BB 4
#define NN 4096
#define KK 16
#define DP 64
#define DM 128
#define DMP 132     // padded LDS row stride (floats); 528 B, 16B-aligned
#define SPITCH 264  // split-tile row stride (shorts): hi[0..127] lo[128..255] pad 8
#define EPSF 1e-8f
#define OUT0N ((size_t)BB * NN * DP)   // elements in out0

typedef unsigned short u16t;
typedef __attribute__((ext_vector_type(8))) short s8v;   // 8 bf16 (4 VGPRs)
typedef __attribute__((ext_vector_type(4))) float f4v;   // MFMA accumulator

__device__ int g_flag;   // 0 = buffers are fp32, 1 = buffers are bf16

__device__ __forceinline__ float u2f(u16t u) {
    unsigned int x = ((unsigned int)u) << 16;
    return __uint_as_float(x);
}
__device__ __forceinline__ u16t f2u(float v) {
    __hip_bfloat16 h = __float2bfloat16(v);
    return *(u16t*)&h;
}
// Exact truncation split: x = u2f(h) + u2f(l) + err, |err| <= 2^-16 |x|.
// hi = x truncated to bf16 (bit mask, exact); lo = x - hi (exact fp32, Dekker);
// lo then truncated to bf16.  4 ALU ops, no rounding sequences.
__device__ __forceinline__ void splitf(float x, u16t& h, u16t& l) {
    const unsigned xb = __float_as_uint(x);
    h = (u16t)(xb >> 16);
    const float hf = __uint_as_float(xb & 0xffff0000u);
    l = (u16t)(__float_as_uint(x - hf) >> 16);
}

// ---------------- dtype-abstracted IO -----------------
template<int DT> struct IO;
template<> struct IO<0> {   // fp32
    static __device__ __forceinline__ float ld(const void* p, size_t i) { return ((const float*)p)[i]; }
    static __device__ __forceinline__ void ld4(const void* p, size_t i, float o[4]) {
        float4 v = *(const float4*)((const float*)p + i);
        o[0] = v.x; o[1] = v.y; o[2] = v.z; o[3] = v.w;
    }
    static __device__ __forceinline__ void st(void* p, size_t i, float v) { ((float*)p)[i] = v; }
};
template<> struct IO<1> {   // bf16
    static __device__ __forceinline__ float ld(const void* p, size_t i) { return u2f(((const u16t*)p)[i]); }
    static __device__ __forceinline__ void ld4(const void* p, size_t i, float o[4]) {
        ushort4 v = *(const ushort4*)((const u16t*)p + i);
        o[0] = u2f(v.x); o[1] = u2f(v.y); o[2] = u2f(v.z); o[3] = u2f(v.w);
    }
    static __device__ __forceinline__ void st(void* p, size_t i, float v) { ((u16t*)p)[i] = f2u(v); }
};

// ---------------- dtype detector ----------------------
__global__ __launch_bounds__(64) void detect_kernel(const void* feat) {
    const int tid = threadIdx.x;
    float x = u2f(((const u16t*)feat)[2 * tid]);
    float a = fabsf(x);
    bool sane = (x == 0.0f) || (a > 1e-4f && a < 50.0f);   // NaN/inf -> false
    unsigned long long m = __ballot(sane);
    if (tid == 0) g_flag = (__popcll(m) >= 32) ? 1 : 0;
}

// ---------------- kernel A (fallback): qkv, 1 pt/block
struct QkvSmem { float sf[DP]; float sx[DM]; };

template<int DT>
__device__ __forceinline__ void qkv_body(QkvSmem& s,
    const void* feat, const void* fc1_w, const void* fc1_b,
    const void* wq, const void* wk, const void* wv,
    float* __restrict__ qbuf, float* __restrict__ kbuf, float* __restrict__ vbuf)
{
    const int bn = blockIdx.x;
    const int tid = threadIdx.x;
    if (tid < DP) s.sf[tid] = IO<DT>::ld(feat, (size_t)bn * DP + tid);
    __syncthreads();
    float x = IO<DT>::ld(fc1_b, tid);
#pragma unroll 4
    for (int i = 0; i < DP; i++) x = fmaf(s.sf[i], IO<DT>::ld(fc1_w, i * DM + tid), x);
    s.sx[tid] = x;
    __syncthreads();
    float q = 0.f, k = 0.f, v = 0.f;
    for (int i0 = 0; i0 < DM; i0 += 4) {
        float4 xv = *(const float4*)&s.sx[i0];
        const float xs[4] = { xv.x, xv.y, xv.z, xv.w };
#pragma unroll
        for (int j = 0; j < 4; j++) {
            q = fmaf(xs[j], IO<DT>::ld(wq, (i0 + j) * DM + tid), q);
            k = fmaf(xs[j], IO<DT>::ld(wk, (i0 + j) * DM + tid), k);
            v = fmaf(xs[j], IO<DT>::ld(wv, (i0 + j) * DM + tid), v);
        }
    }
    qbuf[(size_t)bn * DM + tid] = q;
    kbuf[(size_t)bn * DM + tid] = k;
    vbuf[(size_t)bn * DM + tid] = v;
}

__global__ __launch_bounds__(128) void qkv_kernel(
    const void* feat, const void* fc1_w, const void* fc1_b,
    const void* wq, const void* wk, const void* wv,
    float* qbuf, float* kbuf, float* vbuf)
{
    __shared__ __align__(16) QkvSmem s;
    if (g_flag) qkv_body<1>(s, feat, fc1_w, fc1_b, wq, wk, wv, qbuf, kbuf, vbuf);
    else        qkv_body<0>(s, feat, fc1_w, fc1_b, wq, wk, wv, qbuf, kbuf, vbuf);
}

// ---------------- kernel A': qkv, 16 pts/block (proven) ----
struct Qkv16Smem { float sf[16][DP]; float sx[16][DMP]; };

template<int DT>
__device__ __forceinline__ void qkv16_body(Qkv16Smem& s,
    const void* feat, const void* fc1_w, const void* fc1_b,
    const void* wq, const void* wk, const void* wv,
    float* __restrict__ qbuf, float* __restrict__ kbuf, float* __restrict__ vbuf)
{
    const int pnt0 = blockIdx.x << 4;
    const int tid = threadIdx.x;
    {   // stage 16x64 features, one float4 per thread
        const int r = tid >> 4, c4 = (tid & 15) << 2;
        float o[4];
        IO<DT>::ld4(feat, (size_t)(pnt0 + r) * DP + c4, o);
        s.sf[r][c4 + 0] = o[0]; s.sf[r][c4 + 1] = o[1];
        s.sf[r][c4 + 2] = o[2]; s.sf[r][c4 + 3] = o[3];
    }
    __syncthreads();
    const int c = tid & 127, h = tid >> 7;
    {   // X = feat @ fc1_w + fc1_b, 8 points per thread
        float acc[8];
        const float fb = IO<DT>::ld(fc1_b, c);
#pragma unroll
        for (int pp = 0; pp < 8; pp++) acc[pp] = fb;
        for (int i = 0; i < DP; i++) {
            const float w = IO<DT>::ld(fc1_w, (size_t)i * DM + c);
#pragma unroll
            for (int pp = 0; pp < 8; pp++) acc[pp] = fmaf(s.sf[h * 8 + pp][i], w, acc[pp]);
        }
#pragma unroll
        for (int pp = 0; pp < 8; pp++) s.sx[h * 8 + pp][c] = acc[pp];
    }
    __syncthreads();
    {   // q/k/v = X @ W, 8 points per thread, weights loaded once
        float aq[8], ak[8], av[8];
#pragma unroll
        for (int pp = 0; pp < 8; pp++) { aq[pp] = 0.f; ak[pp] = 0.f; av[pp] = 0.f; }
        for (int i0 = 0; i0 < DM; i0 += 4) {
            float x4[8][4];
#pragma unroll
            for (int pp = 0; pp < 8; pp++) {
                const float4 xv = *(const float4*)&s.sx[h * 8 + pp][i0];
                x4[pp][0] = xv.x; x4[pp][1] = xv.y; x4[pp][2] = xv.z; x4[pp][3] = xv.w;
            }
#pragma unroll
            for (int j = 0; j < 4; j++) {
                const float wqv = IO<DT>::ld(wq, (size_t)(i0 + j) * DM + c);
                const float wkv = IO<DT>::ld(wk, (size_t)(i0 + j) * DM + c);
                const float wvv = IO<DT>::ld(wv, (size_t)(i0 + j) * DM + c);
#pragma unroll
                for (int pp = 0; pp < 8; pp++) {
                    aq[pp] = fmaf(x4[pp][j], wqv, aq[pp]);
                    ak[pp] = fmaf(x4[pp][j], wkv, ak[pp]);
                    av[pp] = fmaf(x4[pp][j], wvv, av[pp]);
                }
            }
        }
#pragma unroll
        for (int pp = 0; pp < 8; pp++) {
            const size_t row = (size_t)(pnt0 + h * 8 + pp) * DM + c;
            qbuf[row] = aq[pp]; kbuf[row] = ak[pp]; vbuf[row] = av[pp];
        }
    }
}

__global__ __launch_bounds__(256) void qkv16_kernel(
    const void* feat, const void* fc1_w, const void* fc1_b,
    const void* wq, const void* wk, const void* wv,
    float* qbuf, float* kbuf, float* vbuf)
{
    __shared__ __align__(16) Qkv16Smem s;
    if (g_flag) qkv16_body<1>(s, feat, fc1_w, fc1_b, wq, wk, wv, qbuf, kbuf, vbuf);
    else        qkv16_body<0>(s, feat, fc1_w, fc1_b, wq, wk, wv, qbuf, kbuf, vbuf);
}

// ---------------- kernel B: knn (wave-per-query) -----
template<int DT>
__device__ __forceinline__ void knn_body(float4* __restrict__ sc,
    const void* xyz, int* dst, int dstride, void* dout, int in_out)
{
    if (in_out) {
        if (DT) { dst = (int*)((u16t*)dout + OUT0N); dstride = (KK * DM) / 2; }
        else    { dst = (int*)((float*)dout + OUT0N); dstride = KK * DM; }
    }
    const int b = blockIdx.x >> 9;             // 512 blocks per batch
    const int tid = threadIdx.x;
    for (int j = tid; j < NN; j += 512) {
        float x = IO<DT>::ld(xyz, ((size_t)b * NN + j) * 3 + 0);
        float y = IO<DT>::ld(xyz, ((size_t)b * NN + j) * 3 + 1);
        float z = IO<DT>::ld(xyz, ((size_t)b * NN + j) * 3 + 2);
        float sq = __fadd_rn(__fadd_rn(__fmul_rn(x, x), __fmul_rn(y, y)), __fmul_rn(z, z));
        sc[j] = make_float4(x, y, z, sq);
    }
    __syncthreads();
    const int lane = tid & 63;
    const int wave = tid >> 6;
    const int r = ((blockIdx.x & 511) << 3) + wave;   // query row within batch
    const float4 qc = sc[r];                          // wave-uniform broadcast

    float d[KK];
    int id[KK];
#pragma unroll
    for (int t = 0; t < KK; t++) { d[t] = 3.4e38f; id[t] = 0x7fffffff; }

    for (int j = lane; j < NN; j += 64) {
        const float4 c = sc[j];
        const float dot = __fadd_rn(__fadd_rn(__fmul_rn(qc.x, c.x), __fmul_rn(qc.y, c.y)),
                                    __fmul_rn(qc.z, c.z));
        const float dist = __fsub_rn(__fadd_rn(qc.w, c.w), __fmul_rn(2.0f, dot));
        if (dist < d[KK - 1]) {
            float cd = dist; int ci = j;
#pragma unroll
            for (int t = 0; t < KK; t++) {
                const bool sw = (cd < d[t]);          // strict: stable ties
                const float od = d[t]; const int oi = id[t];
                d[t]  = sw ? cd : d[t];
                id[t] = sw ? ci : id[t];
                cd = sw ? od : cd;
                ci = sw ? oi : ci;
            }
        }
    }

    // wave merge: 16x pop-min over 64 sorted lists
    const size_t base = (size_t)(b * NN + r) * (size_t)dstride;
#pragma unroll
    for (int t = 0; t < KK; t++) {
        float bd = d[0]; int bi = id[0];
#pragma unroll
        for (int off = 32; off >= 1; off >>= 1) {
            const float od = __shfl_xor(bd, off, 64);
            const int   oi = __shfl_xor(bi, off, 64);
            if (od < bd || (od == bd && oi < bi)) { bd = od; bi = oi; }
        }
        const bool win = (d[0] == bd) && (id[0] == bi);   // unique (dist,idx)
        if (win) {
#pragma unroll
            for (int u = 0; u < KK - 1; u++) { d[u] = d[u + 1]; id[u] = id[u + 1]; }
            d[KK - 1] = 3.4e38f; id[KK - 1] = 0x7fffffff;
        }
        if (lane == t) dst[base + t] = bi;
    }
}

__global__ __launch_bounds__(512) void knn_kernel(
    const void* xyz, int* dst, int dstride, void* dout, int in_out)
{
    __shared__ __align__(16) float4 sc[NN];   // 64 KB
    if (g_flag) knn_body<1>(sc, xyz, dst, dstride, dout, in_out);
    else        knn_body<0>(sc, xyz, dst, dstride, dout, in_out);
}

// ---------------- GEMM tile helper (fallback path) ----
template<int DT>
__device__ __forceinline__ void gemm_tile(const float* __restrict__ IN,
                                          const void* __restrict__ W, int woff,
                                          int kg, int f0, float acc[4][4])
{
#pragma unroll
    for (int a = 0; a < 4; a++)
#pragma unroll
        for (int c = 0; c < 4; c++) acc[a][c] = 0.f;
    for (int i0 = 0; i0 < DM; i0 += 4) {
        float w[4][4];
#pragma unroll
        for (int j = 0; j < 4; j++) IO<DT>::ld4(W, (size_t)woff + (i0 + j) * DM + f0, w[j]);
#pragma unroll
        for (int kk = 0; kk < 4; kk++) {
            float4 x4 = *(const float4*)(IN + (kg * 4 + kk) * DMP + i0);
            const float xs[4] = { x4.x, x4.y, x4.z, x4.w };
#pragma unroll
            for (int ff = 0; ff < 4; ff++)
#pragma unroll
                for (int j = 0; j < 4; j++)
                    acc[kk][ff] = fmaf(xs[j], w[j][ff], acc[kk][ff]);
        }
    }
}

// =====================================================
// Weight prep: pack 4 DMxDM matrices (sim_w[1:], d2_w,
// g1_w, g2_w) into MFMA B-fragment order, split fp32 ->
// hi/lo bf16.  Layout per matrix (16384 shorts hi, then
// 16384 shorts lo): frag offset ((tile*4+ks)*64+lane)*8,
// element j = W[ks*32+(lane>>4)*8+j][tile*16+(lane&15)].
// =====================================================
template<int DT>
__device__ __forceinline__ void wprep_body(const void* sim_w, const void* d2_w,
                                           const void* g1_w, const void* g2_w,
                                           u16t* __restrict__ wprep)
{
    const int m  = blockIdx.x >> 3;    // matrix 0..3
    const int t  = blockIdx.x & 7;     // col tile 0..7
    const int ks = threadIdx.x >> 6;   // k-step 0..3
    const int lane = threadIdx.x & 63;
    const void* src = (m == 0) ? sim_w : (m == 1) ? d2_w : (m == 2) ? g1_w : g2_w;
    const int srcoff = (m == 0) ? DM : 0;   // sim_w: skip row 0 (handled in epilogue)
    u16t* hi = wprep + (size_t)m * 32768;
    u16t* lo = hi + 16384;
    const int c  = t * 16 + (lane & 15);
    const int k0 = ks * 32 + ((lane >> 4) << 3);
    s8v vh, vl;
#pragma unroll
    for (int j = 0; j < 8; j++) {
        const float x = IO<DT>::ld(src, (size_t)srcoff + (size_t)(k0 + j) * DM + c);
        const u16t h = f2u(x);
        vh[j] = (short)h;
        vl[j] = (short)f2u(x - u2f(h));
    }
    const size_t off = ((size_t)(t * 4 + ks) * 64 + lane) * 8;
    *(s8v*)(hi + off) = vh;
    *(s8v*)(lo + off) = vl;
}

__global__ __launch_bounds__(256) void wprep_kernel(
    const void* sim_w, const void* d2_w, const void* g1_w, const void* g2_w,
    u16t* wprep)
{
    if (g_flag) wprep_body<1>(sim_w, d2_w, g1_w, g2_w, wprep);
    else        wprep_body<0>(sim_w, d2_w, g1_w, g2_w, wprep);
}

// =====================================================
// MFMA core: A pre-split in LDS (SP: hi plane cols 0..127,
// lo plane cols 128..255, row stride SPITCH shorts).
// 2 waves: wave wid covers col tiles 4*wid..4*wid+3.
// Layouts (v_mfma_f32_16x16x32_bf16, m89-verified):
//   A: row = lane&15, k = ks*32 + (lane>>4)*8 + j
//   B: col = lane&15, k = ks*32 + (lane>>4)*8 + j
//   D: col = lane&15, row = (lane>>4)*4 + r
// =====================================================
__device__ __forceinline__ void mfma_core(const u16t* __restrict__ SP,
                                          const u16t* __restrict__ wmat,
                                          int lane, int wid, f4v acc[4])
{
    const u16t* whi = wmat;
    const u16t* wlo = wmat + 16384;
    const u16t* ar = SP + (size_t)(lane & 15) * SPITCH + ((lane >> 4) << 3);
#pragma unroll
    for (int ks = 0; ks < 4; ks++) {
        const s8v ahi = *(const s8v*)(ar + ks * 32);
        const s8v alo = *(const s8v*)(ar + 128 + ks * 32);
#pragma unroll
        for (int t = 0; t < 4; t++) {
            const size_t off = ((size_t)((wid * 4 + t) * 4 + ks) * 64 + lane) * 8;
            const s8v bhi = *(const s8v*)(whi + off);
            const s8v blo = *(const s8v*)(wlo + off);
            acc[t] = __builtin_amdgcn_mfma_f32_16x16x32_bf16(ahi, bhi, acc[t], 0, 0, 0);
            acc[t] = __builtin_amdgcn_mfma_f32_16x16x32_bf16(ahi, blo, acc[t], 0, 0, 0);
            acc[t] = __builtin_amdgcn_mfma_f32_16x16x32_bf16(alo, bhi, acc[t], 0, 0, 0);
        }
    }
}

// ---------------- kernel C: MFMA attn, 1 pt/block ----
// 128 threads (2 waves), ~27 KB LDS -> 5 blocks/CU.
// All GEMM A-operands are split ONCE by their producer
// phase into SP (bf16 hi/lo planes); MFMA reads directly.
struct AttnSmemS {
    float KF[KK * DMP];        // K gather -> later PE
    float T1[KK * DMP];        // rel_qk  -> later GEMM4 out
    u16t  SP[KK * SPITCH];     // split A-tile (shared by all 4 GEMMs)
    float s_q[DM];
    float sred[DM];            // einsum result
    float sp2[DM];             // fc2 partials
    float srp[KK][3];
    float ssim[KK];
    int   sidx[KK];
};

template<int DT>
__device__ __forceinline__ void attn_sp_body(AttnSmemS& s,
    const void* xyz, const void* feat,
    const void* fc2_w, const void* fc2_b,
    const void* d1_w, const void* d1_b, const void* d2_b,
    const void* g1_b, const void* g2_b,
    const void* sim_w, const void* sim_b,
    const float* __restrict__ qbuf, const float* __restrict__ kbuf,
    const float* __restrict__ vbuf,
    const int* __restrict__ knn, const u16t* __restrict__ wprep, void* dout)
{
    void* out0 = dout;
    void* out1 = DT ? (void*)((u16t*)dout + OUT0N) : (void*)((float*)dout + OUT0N);
    const int bn = blockIdx.x;
    const int b = bn >> 12;
    const int tid = threadIdx.x;
    const int f = tid;
    const int lane = tid & 63;
    const int wid = tid >> 6;

    if (tid < KK) {
        int sv = knn[(size_t)bn * KK + tid];
        sv = (sv < 0) ? 0 : (sv > NN - 1 ? NN - 1 : sv);
        s.sidx[tid] = sv;
    }
    __syncthreads();

    // gather q, K; prefetch V into registers (consumed at the einsum)
    float vreg[KK];
    {
        s.s_q[f] = qbuf[(size_t)bn * DM + f];
#pragma unroll
        for (int k = 0; k < KK; k++) {
            const int grow = (b << 12) + s.sidx[k];
            s.KF[k * DMP + f] = kbuf[(size_t)grow * DM + f];
            vreg[k] = vbuf[(size_t)grow * DM + f];
        }
    }
    if (tid < KK) {
        const int grow = (b << 12) + s.sidx[tid];
#pragma unroll
        for (int c = 0; c < 3; c++)
            s.srp[tid][c] = IO<DT>::ld(xyz, (size_t)bn * 3 + c) - IO<DT>::ld(xyz, (size_t)grow * 3 + c);
    }
    __syncthreads();

    // MERGED: norms/sim (8-lane groups) + SP = split(q - K) (row-per-thread)
    {
        const int j = tid >> 3, g = tid & 7;
        float sk = 0.f, sd = 0.f, qq = 0.f;
#pragma unroll
        for (int i4 = 0; i4 < 16; i4 += 4) {
            const float4 kv = *(const float4*)&s.KF[j * DMP + g * 16 + i4];
            const float4 qv = *(const float4*)&s.s_q[g * 16 + i4];
            sk = fmaf(kv.x, kv.x, fmaf(kv.y, kv.y, fmaf(kv.z, kv.z, fmaf(kv.w, kv.w, sk))));
            sd = fmaf(qv.x, kv.x, fmaf(qv.y, kv.y, fmaf(qv.z, kv.z, fmaf(qv.w, kv.w, sd))));
            qq = fmaf(qv.x, qv.x, fmaf(qv.y, qv.y, fmaf(qv.z, qv.z, fmaf(qv.w, qv.w, qq))));
        }
#pragma unroll
        for (int off = 1; off <= 4; off <<= 1) {
            sk += __shfl_xor(sk, off, 64);
            sd += __shfl_xor(sd, off, 64);
            qq += __shfl_xor(qq, off, 64);
        }
        if (g == 0) {
            const float qn = fmaxf(sqrtf(qq), EPSF);
            const float kn = fmaxf(sqrtf(sk), EPSF);
            s.ssim[j] = sd / (qn * kn);
        }
    }
    {
        const int r = tid & 15, c0 = (tid >> 4) << 4;
        u16t* hp = &s.SP[r * SPITCH + c0];
        u16t* lp = hp + 128;
#pragma unroll
        for (int j4 = 0; j4 < 16; j4 += 4) {
            const float4 kv = *(const float4*)&s.KF[r * DMP + c0 + j4];
            const float4 qv = *(const float4*)&s.s_q[c0 + j4];
            ushort4 hv, lv;
            splitf(qv.x - kv.x, hv.x, lv.x);
            splitf(qv.y - kv.y, hv.y, lv.y);
            splitf(qv.z - kv.z, hv.z, lv.z);
            splitf(qv.w - kv.w, hv.w, lv.w);
            *(ushort4*)(hp + j4) = hv;
            *(ushort4*)(lp + j4) = lv;
        }
    }
    __syncthreads();

    // GEMM1: T1 = [sim, q-k] @ sim_w + sim_b  (sim row folded via w0)
    {
        f4v acc[4] = { {0,0,0,0},{0,0,0,0},{0,0,0,0},{0,0,0,0} };
        mfma_core(s.SP, wprep + 0 * 32768, lane, wid, acc);
        const int r0 = (lane >> 4) * 4;
#pragma unroll
        for (int t = 0; t < 4; t++) {
            const int col = (wid * 4 + t) * 16 + (lane & 15);
            const float bv = IO<DT>::ld(sim_b, col);
            const float w0v = IO<DT>::ld(sim_w, col);
#pragma unroll
            for (int r = 0; r < 4; r++)
                s.T1[(size_t)(r0 + r) * DMP + col] = fmaf(s.ssim[r0 + r], w0v, acc[t][r] + bv);
        }
    }
    __syncthreads();

    // SP = split(relu(rel_pos @ d1_w + d1_b))
    {
        const int r = tid & 15, c0 = (tid >> 4) << 4;
        const float rx = s.srp[r][0], ry = s.srp[r][1], rz = s.srp[r][2];
        u16t* hp = &s.SP[r * SPITCH + c0];
        u16t* lp = hp + 128;
#pragma unroll
        for (int j4 = 0; j4 < 16; j4 += 4) {
            float w0[4], w1[4], w2[4], bb[4];
            IO<DT>::ld4(d1_w, (size_t)0 * DM + c0 + j4, w0);
            IO<DT>::ld4(d1_w, (size_t)1 * DM + c0 + j4, w1);
            IO<DT>::ld4(d1_w, (size_t)2 * DM + c0 + j4, w2);
            IO<DT>::ld4(d1_b, c0 + j4, bb);
            ushort4 hv, lv;
#pragma unroll
            for (int jj = 0; jj < 4; jj++) {
                const float h = fmaxf(fmaf(rz, w2[jj], fmaf(ry, w1[jj], fmaf(rx, w0[jj], bb[jj]))), 0.f);
                u16t hs, ls; splitf(h, hs, ls);
                ((u16t*)&hv)[jj] = hs; ((u16t*)&lv)[jj] = ls;
            }
            *(ushort4*)(hp + j4) = hv;
            *(ushort4*)(lp + j4) = lv;
        }
    }
    __syncthreads();

    // GEMM2: KF = pos_enc = h @ d2_w + d2_b   (K values dead)
    {
        f4v acc[4] = { {0,0,0,0},{0,0,0,0},{0,0,0,0},{0,0,0,0} };
        mfma_core(s.SP, wprep + 1 * 32768, lane, wid, acc);
        const int r0 = (lane >> 4) * 4;
#pragma unroll
        for (int t = 0; t < 4; t++) {
            const int col = (wid * 4 + t) * 16 + (lane & 15);
            const float bv = IO<DT>::ld(d2_b, col);
#pragma unroll
            for (int r = 0; r < 4; r++)
                s.KF[(size_t)(r0 + r) * DMP + col] = acc[t][r] + bv;
        }
    }
    __syncthreads();

    // SP = split(T1 + KF)   (rel_qk + pos_enc)
    {
        const int r = tid & 15, c0 = (tid >> 4) << 4;
        u16t* hp = &s.SP[r * SPITCH + c0];
        u16t* lp = hp + 128;
#pragma unroll
        for (int j4 = 0; j4 < 16; j4 += 4) {
            const float4 t4 = *(const float4*)&s.T1[r * DMP + c0 + j4];
            const float4 p4 = *(const float4*)&s.KF[r * DMP + c0 + j4];
            ushort4 hv, lv;
            splitf(t4.x + p4.x, hv.x, lv.x);
            splitf(t4.y + p4.y, hv.y, lv.y);
            splitf(t4.z + p4.z, hv.z, lv.z);
            splitf(t4.w + p4.w, hv.w, lv.w);
            *(ushort4*)(hp + j4) = hv;
            *(ushort4*)(lp + j4) = lv;
        }
    }
    __syncthreads();

    // GEMM3: relu(@g1_w + g1_b) -> split, scattered back into SP
    {
        f4v acc[4] = { {0,0,0,0},{0,0,0,0},{0,0,0,0},{0,0,0,0} };
        mfma_core(s.SP, wprep + 2 * 32768, lane, wid, acc);
        __syncthreads();   // all waves done READING SP before overwrite
        const int r0 = (lane >> 4) * 4;
#pragma unroll
        for (int t = 0; t < 4; t++) {
            const int col = (wid * 4 + t) * 16 + (lane & 15);
            const float bv = IO<DT>::ld(g1_b, col);
#pragma unroll
            for (int r = 0; r < 4; r++) {
                const float v = fmaxf(acc[t][r] + bv, 0.f);
                u16t hs, ls; splitf(v, hs, ls);
                s.SP[(size_t)(r0 + r) * SPITCH + col] = hs;
                s.SP[(size_t)(r0 + r) * SPITCH + 128 + col] = ls;
            }
        }
    }
    __syncthreads();

    // GEMM4: T1 = @g2_w + g2_b
    {
        f4v acc[4] = { {0,0,0,0},{0,0,0,0},{0,0,0,0},{0,0,0,0} };
        mfma_core(s.SP, wprep + 3 * 32768, lane, wid, acc);
        const int r0 = (lane >> 4) * 4;
#pragma unroll
        for (int t = 0; t < 4; t++) {
            const int col = (wid * 4 + t) * 16 + (lane & 15);
            const float bv = IO<DT>::ld(g2_b, col);
#pragma unroll
            for (int r = 0; r < 4; r++)
                s.T1[(size_t)(r0 + r) * DMP + col] = acc[t][r] + bv;
        }
    }
    __syncthreads();

    // softmax over K + einsum (V from prefetched regs, PE from KF)
    {
        const float inv = 0.08838834764831843f;   // 1/sqrt(128)
        float tv[KK];
        float mx = -3.4e38f;
#pragma unroll
        for (int k = 0; k < KK; k++) { tv[k] = s.T1[k * DMP + f] * inv; mx = fmaxf(mx, tv[k]); }
        float ssum = 0.f;
#pragma unroll
        for (int k = 0; k < KK; k++) { tv[k] = __expf(tv[k] - mx); ssum += tv[k]; }
        const float rs = 1.0f / ssum;
        float rf = 0.f;
#pragma unroll
        for (int k = 0; k < KK; k++) {
            const float a = tv[k] * rs;
            IO<DT>::st(out1, ((size_t)bn * KK + k) * DM + f, a);
            rf = fmaf(a, vreg[k] + s.KF[k * DMP + f], rf);
        }
        s.sred[f] = rf;
    }
    __syncthreads();

    // out0 = res @ fc2_w + fc2_b + features (both waves: i-halves)
    {
        const int c = tid & 63, hh = tid >> 6;
        float o = 0.f;
        for (int i = hh * 64; i < hh * 64 + 64; i++)
            o = fmaf(s.sred[i], IO<DT>::ld(fc2_w, (size_t)i * DP + c), o);
        s.sp2[tid] = o;
    }
    __syncthreads();
    if (tid < DP) {
        float o = s.sp2[tid] + s.sp2[tid + 64];
        o = o + IO<DT>::ld(fc2_b, tid) + IO<DT>::ld(feat, (size_t)bn * DP + tid);
        IO<DT>::st(out0, (size_t)bn * DP + tid, o);
    }
}

__global__ __launch_bounds__(128) void attn_sp_kernel(
    const void* xyz, const void* feat,
    const void* fc2_w, const void* fc2_b,
    const void* d1_w, const void* d1_b, const void* d2_b,
    const void* g1_b, const void* g2_b,
    const void* sim_w, const void* sim_b,
    const float* qbuf, const float* kbuf, const float* vbuf,
    const int* knn, const u16t* wprep, void* dout)
{
    __shared__ __align__(16) AttnSmemS s;
    if (g_flag)
        attn_sp_body<1>(s, xyz, feat, fc2_w, fc2_b, d1_w, d1_b, d2_b, g1_b, g2_b,
                        sim_w, sim_b, qbuf, kbuf, vbuf, knn, wprep, dout);
    else
        attn_sp_body<0>(s, xyz, feat, fc2_w, fc2_b, d1_w, d1_b, d2_b, g1_b, g2_b,
                        sim_w, sim_b, qbuf, kbuf, vbuf, knn, wprep, dout);
}

// ---------------- kernel C: attn (fallback paths) ----
template<bool FUSED> struct AttnSmem {
    float Kb[KK * DMP], Vb[KK * DMP], PE[KK * DMP], T0[KK * DMP], T1[KK * DMP];
    float s_q[DM], sres[DM];
    float SF[FUSED ? 17 * DP : 1];
    float X[FUSED ? 17 * DMP : 1];
    float srp[KK][3];
    float ssim[KK], skn[KK], sdot[KK];
    float sqn;
    int sidx[KK];
};

template<int DT, bool FUSED>
__device__ __forceinline__ void attn_body(AttnSmem<FUSED>& s,
    const void* xyz, const void* feat,
    const void* fc1_w, const void* fc1_b, const void* fc2_w, const void* fc2_b,
    const void* d1_w, const void* d1_b, const void* d2_w, const void* d2_b,
    const void* g1_w, const void* g1_b, const void* g2_w, const void* g2_b,
    const void* sim_w, const void* sim_b,
    const void* wq, const void* wk, const void* wv,
    const float* __restrict__ qbuf, const float* __restrict__ kbuf, const float* __restrict__ vbuf,
    const int* knn, int knn_stride, int knn_in_out, void* dout)
{
    void* out0 = dout;
    void* out1 = DT ? (void*)((u16t*)dout + OUT0N) : (void*)((float*)dout + OUT0N);
    if (knn_in_out) {
        if (DT) { knn = (const int*)((const u16t*)dout + OUT0N); knn_stride = (KK * DM) / 2; }
        else    { knn = (const int*)((const float*)dout + OUT0N); knn_stride = KK * DM; }
    }

    const int bn = blockIdx.x;
    const int b = bn >> 12;
    const int tid = threadIdx.x;
    const int f = tid;
    const int f0 = (tid & 31) * 4;
    const int kg = tid >> 5;

    if (tid < KK) {
        int sv = knn[(size_t)bn * knn_stride + tid];
        sv = (sv < 0) ? 0 : (sv > NN - 1 ? NN - 1 : sv);   // defensive, never OOB
        s.sidx[tid] = sv;
    }
    __syncthreads();

    if constexpr (FUSED) {
        for (int idx = tid; idx < 17 * DP; idx += 128) {
            const int r = idx >> 6, c = idx & 63;
            const int row = (r < KK) ? ((b << 12) + s.sidx[r]) : bn;
            s.SF[idx] = IO<DT>::ld(feat, (size_t)row * DP + c);
        }
        __syncthreads();
        float xacc[17];
        const float fb = IO<DT>::ld(fc1_b, tid);
#pragma unroll
        for (int r = 0; r < 17; r++) xacc[r] = fb;
        for (int i = 0; i < DP; i++) {
            const float w = IO<DT>::ld(fc1_w, i * DM + tid);
#pragma unroll
            for (int r = 0; r < 17; r++) xacc[r] = fmaf(s.SF[r * DP + i], w, xacc[r]);
        }
#pragma unroll
        for (int r = 0; r < 17; r++) s.X[r * DMP + tid] = xacc[r];
        __syncthreads();
        {
            float a2[4][4];
            gemm_tile<DT>(s.X, wk, 0, kg, f0, a2);
#pragma unroll
            for (int kk = 0; kk < 4; kk++)
                *(float4*)&s.Kb[(kg * 4 + kk) * DMP + f0] =
                    make_float4(a2[kk][0], a2[kk][1], a2[kk][2], a2[kk][3]);
            gemm_tile<DT>(s.X, wv, 0, kg, f0, a2);
#pragma unroll
            for (int kk = 0; kk < 4; kk++)
                *(float4*)&s.Vb[(kg * 4 + kk) * DMP + f0] =
                    make_float4(a2[kk][0], a2[kk][1], a2[kk][2], a2[kk][3]);
        }
        {
            float qv = 0.f;
            for (int i0 = 0; i0 < DM; i0 += 4) {
                float4 x4 = *(const float4*)&s.X[16 * DMP + i0];
                const float xs[4] = { x4.x, x4.y, x4.z, x4.w };
#pragma unroll
                for (int j = 0; j < 4; j++)
                    qv = fmaf(xs[j], IO<DT>::ld(wq, (i0 + j) * DM + tid), qv);
            }
            s.s_q[tid] = qv;
        }
    } else {
        s.s_q[f] = qbuf[(size_t)bn * DM + f];
#pragma unroll
        for (int k = 0; k < KK; k++) {
            const int row = (b << 12) + s.sidx[k];
            s.Kb[k * DMP + f] = kbuf[(size_t)row * DM + f];
            s.Vb[k * DMP + f] = vbuf[(size_t)row * DM + f];
        }
    }
    if (tid < KK) {
        const int row = (b << 12) + s.sidx[tid];
#pragma unroll
        for (int c = 0; c < 3; c++)
            s.srp[tid][c] = IO<DT>::ld(xyz, (size_t)bn * 3 + c) - IO<DT>::ld(xyz, (size_t)row * 3 + c);
    }
    __syncthreads();

    // norms + q.k dots
    if (tid < KK) {
        float sk = 0.f, sd = 0.f;
        for (int i = 0; i < DM; i++) {
            float v2 = s.Kb[tid * DMP + i];
            sk = fmaf(v2, v2, sk);
            sd = fmaf(s.s_q[i], v2, sd);
        }
        s.skn[tid] = fmaxf(sqrtf(sk), EPSF);
        s.sdot[tid] = sd;
    } else if (tid == KK) {
        float sqq = 0.f;
        for (int i = 0; i < DM; i++) { float v2 = s.s_q[i]; sqq = fmaf(v2, v2, sqq); }
        s.sqn = fmaxf(sqrtf(sqq), EPSF);
    }
    __syncthreads();
    if (tid < KK) s.ssim[tid] = s.sdot[tid] / (s.sqn * s.skn[tid]);
#pragma unroll
    for (int k = 0; k < KK; k++) s.T0[k * DMP + f] = s.s_q[f] - s.Kb[k * DMP + f];
    __syncthreads();

    float acc[4][4];

    // rel_qk = [sim, q-k] @ sim_w + sim_b  -> T1
    gemm_tile<DT>(s.T0, sim_w, DM, kg, f0, acc);
    {
        float w0f[4], sbf[4];
        IO<DT>::ld4(sim_w, f0, w0f);
        IO<DT>::ld4(sim_b, f0, sbf);
#pragma unroll
        for (int kk = 0; kk < 4; kk++) {
            float sm = s.ssim[kg * 4 + kk];
            float4 o;
            o.x = fmaf(sm, w0f[0], acc[kk][0]) + sbf[0];
            o.y = fmaf(sm, w0f[1], acc[kk][1]) + sbf[1];
            o.z = fmaf(sm, w0f[2], acc[kk][2]) + sbf[2];
            o.w = fmaf(sm, w0f[3], acc[kk][3]) + sbf[3];
            *(float4*)&s.T1[(kg * 4 + kk) * DMP + f0] = o;
        }
    }
    __syncthreads();

    // h = relu(rel_pos @ d1_w + d1_b) -> T0
    {
        float w0 = IO<DT>::ld(d1_w, 0 * DM + f), w1 = IO<DT>::ld(d1_w, 1 * DM + f),
              w2 = IO<DT>::ld(d1_w, 2 * DM + f);
        float hb = IO<DT>::ld(d1_b, f);
#pragma unroll
        for (int k = 0; k < KK; k++) {
            float h = fmaf(s.srp[k][2], w2, fmaf(s.srp[k][1], w1, fmaf(s.srp[k][0], w0, hb)));
            s.T0[k * DMP + f] = fmaxf(h, 0.f);
        }
    }
    __syncthreads();

    // pos_enc = h @ d2_w + d2_b -> PE
    gemm_tile<DT>(s.T0, d2_w, 0, kg, f0, acc);
    {
        float bf[4];
        IO<DT>::ld4(d2_b, f0, bf);
#pragma unroll
        for (int kk = 0; kk < 4; kk++)
            *(float4*)&s.PE[(kg * 4 + kk) * DMP + f0] =
                make_float4(acc[kk][0] + bf[0], acc[kk][1] + bf[1],
                            acc[kk][2] + bf[2], acc[kk][3] + bf[3]);
    }
    __syncthreads();

    // T0 = T1 + PE
#pragma unroll
    for (int kk = 0; kk < 4; kk++) {
        const int row = (kg * 4 + kk) * DMP + f0;
        float4 a4 = *(const float4*)&s.T1[row];
        float4 p4 = *(const float4*)&s.PE[row];
        *(float4*)&s.T0[row] = make_float4(a4.x + p4.x, a4.y + p4.y, a4.z + p4.z, a4.w + p4.w);
    }
    __syncthreads();

    // T1 = relu(T0 @ g1_w + g1_b)
    gemm_tile<DT>(s.T0, g1_w, 0, kg, f0, acc);
    {
        float bf[4];
        IO<DT>::ld4(g1_b, f0, bf);
#pragma unroll
        for (int kk = 0; kk < 4; kk++)
            *(float4*)&s.T1[(kg * 4 + kk) * DMP + f0] =
                make_float4(fmaxf(acc[kk][0] + bf[0], 0.f), fmaxf(acc[kk][1] + bf[1], 0.f),
                            fmaxf(acc[kk][2] + bf[2], 0.f), fmaxf(acc[kk][3] + bf[3], 0.f));
    }
    __syncthreads();

    // T0 = T1 @ g2_w + g2_b
    gemm_tile<DT>(s.T1, g2_w, 0, kg, f0, acc);
    {
        float bf[4];
        IO<DT>::ld4(g2_b, f0, bf);
#pragma unroll
        for (int kk = 0; kk < 4; kk++)
            *(float4*)&s.T0[(kg * 4 + kk) * DMP + f0] =
                make_float4(acc[kk][0] + bf[0], acc[kk][1] + bf[1],
                            acc[kk][2] + bf[2], acc[kk][3] + bf[3]);
    }
    __syncthreads();

    // softmax over K + einsum
    {
        const float sq128 = 11.31370849898476f;
        float tv[KK];
        float m = -3.4e38f;
#pragma unroll
        for (int k = 0; k < KK; k++) { tv[k] = s.T0[k * DMP + f] / sq128; m = fmaxf(m, tv[k]); }
        float ssum = 0.f;
#pragma unroll
        for (int k = 0; k < KK; k++) { tv[k] = expf(tv[k] - m); ssum += tv[k]; }
        float rf = 0.f;
#pragma unroll
        for (int k = 0; k < KK; k++) {
            float a = tv[k] / ssum;
            IO<DT>::st(out1, ((size_t)bn * KK + k) * DM + f, a);
            rf = fmaf(a, s.Vb[k * DMP + f] + s.PE[k * DMP + f], rf);
        }
        s.sres[f] = rf;
    }
    __syncthreads();

    // out0 = res @ fc2_w + fc2_b + features
    if (tid < DP) {
        float o = 0.f;
        for (int i = 0; i < DM; i++) o = fmaf(s.sres[i], IO<DT>::ld(fc2_w, i * DP + tid), o);
        o = o + IO<DT>::ld(fc2_b, tid) + IO<DT>::ld(feat, (size_t)bn * DP + tid);
        IO<DT>::st(out0, (size_t)bn * DP + tid, o);
    }
}

template<bool FUSED>
__global__ __launch_bounds__(128) void attn_kernel(
    const void* xyz, const void* feat,
    const void* fc1_w, const void* fc1_b, const void* fc2_w, const void* fc2_b,
    const void* d1_w, const void* d1_b, const void* d2_w, const void* d2_b,
    const void* g1_w, const void* g1_b, const void* g2_w, const void* g2_b,
    const void* sim_w, const void* sim_b,
    const void* wq, const void* wk, const void* wv,
    const float* qbuf, const float* kbuf, const float* vbuf,
    const int* knn, int knn_stride, int knn_in_out, void* dout)
{
    __shared__ __align__(16) AttnSmem<FUSED> s;
    if (g_flag)
        attn_body<1, FUSED>(s, xyz, feat, fc1_w, fc1_b, fc2_w, fc2_b, d1_w, d1_b, d2_w, d2_b,
                            g1_w, g1_b, g2_w, g2_b, sim_w, sim_b, wq, wk, wv,
                            qbuf, kbuf, vbuf, knn, knn_stride, knn_in_out, dout);
    else
        attn_body<0, FUSED>(s, xyz, feat, fc1_w, fc1_b, fc2_w, fc2_b, d1_w, d1_b, d2_w, d2_b,
                            g1_w, g1_b, g2_w, g2_b, sim_w, sim_b, wq, wk, wv,
                            qbuf, kbuf, vbuf, knn, knn_stride, knn_in_out, dout);
}

// ---------------------------------------------------------------- launch
extern "C" void kernel_launch(void* const* d_in, const int* in_sizes, int n_in,
                              void* d_out, int out_size, void* d_ws, size_t ws_size,
                              hipStream_t stream)
{
    const void* xyz   = d_in[0];
    const void* feat  = d_in[1];
    const void* fc1_w = d_in[2];
    const void* fc1_b = d_in[3];
    const void* fc2_w = d_in[4];
    const void* fc2_b = d_in[5];
    const void* d1_w  = d_in[6];
    const void* d1_b  = d_in[7];
    const void* d2_w  = d_in[8];
    const void* d2_b  = d_in[9];
    const void* g1_w  = d_in[10];
    const void* g1_b  = d_in[11];
    const void* g2_w  = d_in[12];
    const void* g2_b  = d_in[13];
    const void* wq_w  = d_in[14];
    const void* wk_w  = d_in[15];
    const void* wv_w  = d_in[16];
    const void* sim_w = d_in[17];
    const void* sim_b = d_in[18];

    detect_kernel<<<1, 64, 0, stream>>>(feat);

    const size_t need_qkv = (size_t)3 * BB * NN * DM * sizeof(float);
    const size_t need_knn = (size_t)BB * NN * KK * sizeof(int);
    const size_t need_wp  = (size_t)4 * 2 * 16384 * sizeof(u16t);   // 256 KB packed weights

    if (ws_size >= need_qkv + need_knn + need_wp && d_ws != nullptr) {
        float* qbuf  = (float*)d_ws;
        float* kbuf  = qbuf + (size_t)BB * NN * DM;
        float* vbuf  = kbuf + (size_t)BB * NN * DM;
        int*   knn   = (int*)(vbuf + (size_t)BB * NN * DM);
        u16t*  wprep = (u16t*)(knn + (size_t)BB * NN * KK);
        qkv16_kernel<<<(BB * NN) / 16, 256, 0, stream>>>(feat, fc1_w, fc1_b, wq_w, wk_w, wv_w,
                                                         qbuf, kbuf, vbuf);
        knn_kernel<<<BB * 512, 512, 0, stream>>>(xyz, knn, KK, d_out, 0);
        wprep_kernel<<<32, 256, 0, stream>>>(sim_w, d2_w, g1_w, g2_w, wprep);
        attn_sp_kernel<<<BB * NN, 128, 0, stream>>>(
            xyz, feat, fc2_w, fc2_b, d1_w, d1_b, d2_b, g1_b, g2_b, sim_w, sim_b,
            qbuf, kbuf, vbuf, knn, wprep, d_out);
    } else if (ws_size >= need_qkv + need_knn && d_ws != nullptr) {
        float* qbuf = (float*)d_ws;
        float* kbuf = qbuf + (size_t)BB * NN * DM;
        float* vbuf = kbuf + (size_t)BB * NN * DM;
        int*   knn  = (int*)(vbuf + (size_t)BB * NN * DM);
        qkv_kernel<<<BB * NN, DM, 0, stream>>>(feat, fc1_w, fc1_b, wq_w, wk_w, wv_w, qbuf, kbuf, vbuf);
        knn_kernel<<<BB * 512, 512, 0, stream>>>(xyz, knn, KK, d_out, 0);
        attn_kernel<false><<<BB * NN, DM, 0, stream>>>(
            xyz, feat, fc1_w, fc1_b, fc2_w, fc2_b, d1_w, d1_b, d2_w, d2_b,
            g1_w, g1_b, g2_w, g2_b, sim_w, sim_b, wq_w, wk_w, wv_w,
            qbuf, kbuf, vbuf, knn, KK, 0, d_out);
    } else if (ws_size >= need_knn && d_ws != nullptr) {
        int* knn = (int*)d_ws;
        knn_kernel<<<BB * 512, 512, 0, stream>>>(xyz, knn, KK, d_out, 0);
        attn_kernel<true><<<BB * NN, DM, 0, stream>>>(
            xyz, feat, fc1_w, fc1_b, fc2_w, fc2_b, d1_w, d1_b, d2_w, d2_b,
            g1_w, g1_b, g2_w, g2_b, sim_w, sim_b, wq_w, wk_w, wv_w,
            nullptr, nullptr, nullptr, knn, KK, 0, d_out);
    } else {
        knn_kernel<<<BB * 512, 512, 0, stream>>>(xyz, nullptr, 0, d_out, 1);
        attn_kernel<true><<<BB * NN, DM, 0, stream>>>(
            xyz, feat, fc1_w, fc1_b, fc2_w, fc2_b, d1_w, d1_b, d2_w, d2_b,
            g1_w, g1_b, g2_w, g2_b, sim_w, sim_b, wq_w, wk_w, wv_w,
            nullptr, nullptr, nullptr, nullptr, 0, 1, d_out);
    }
}

// Round 4
// 579.103 us; speedup vs baseline: 1.2188x; 1.1138x over previous
//
#include <hip/hip_runtime.h>
#include <hip/hip_bf16.h>

#define BB 4
#define NN 4096
#define KK 16
#define DP 64
#define DM 128
#define DMP 132     // padded LDS row stride (floats); 528 B, 16B-aligned
#define SPITCH 264  // split-tile row stride (shorts): hi[0..127] lo[128..255] pad 8
#define EPSF 1e-8f
#define OUT0N ((size_t)BB * NN * DP)   // elements in out0

typedef unsigned short u16t;
typedef __attribute__((ext_vector_type(8))) short s8v;   // 8 bf16 (4 VGPRs)
typedef __attribute__((ext_vector_type(4))) float f4v;   // MFMA accumulator

__device__ int g_flag;   // 0 = buffers are fp32, 1 = buffers are bf16

__device__ __forceinline__ float u2f(u16t u) {
    unsigned int x = ((unsigned int)u) << 16;
    return __uint_as_float(x);
}
__device__ __forceinline__ u16t f2u(float v) {
    __hip_bfloat16 h = __float2bfloat16(v);
    return *(u16t*)&h;
}
// Exact truncation split: x = u2f(h) + u2f(l) + err, |err| <= 2^-16 |x|.
__device__ __forceinline__ void splitf(float x, u16t& h, u16t& l) {
    const unsigned xb = __float_as_uint(x);
    h = (u16t)(xb >> 16);
    const float hf = __uint_as_float(xb & 0xffff0000u);
    l = (u16t)(__float_as_uint(x - hf) >> 16);
}

// ---------------- dtype-abstracted IO -----------------
template<int DT> struct IO;
template<> struct IO<0> {   // fp32
    static __device__ __forceinline__ float ld(const void* p, size_t i) { return ((const float*)p)[i]; }
    static __device__ __forceinline__ void ld4(const void* p, size_t i, float o[4]) {
        float4 v = *(const float4*)((const float*)p + i);
        o[0] = v.x; o[1] = v.y; o[2] = v.z; o[3] = v.w;
    }
    static __device__ __forceinline__ void st(void* p, size_t i, float v) { ((float*)p)[i] = v; }
};
template<> struct IO<1> {   // bf16
    static __device__ __forceinline__ float ld(const void* p, size_t i) { return u2f(((const u16t*)p)[i]); }
    static __device__ __forceinline__ void ld4(const void* p, size_t i, float o[4]) {
        ushort4 v = *(const ushort4*)((const u16t*)p + i);
        o[0] = u2f(v.x); o[1] = u2f(v.y); o[2] = u2f(v.z); o[3] = u2f(v.w);
    }
    static __device__ __forceinline__ void st(void* p, size_t i, float v) { ((u16t*)p)[i] = f2u(v); }
};

// ---------------- dtype detector ----------------------
__global__ __launch_bounds__(64) void detect_kernel(const void* feat) {
    const int tid = threadIdx.x;
    float x = u2f(((const u16t*)feat)[2 * tid]);
    float a = fabsf(x);
    bool sane = (x == 0.0f) || (a > 1e-4f && a < 50.0f);   // NaN/inf -> false
    unsigned long long m = __ballot(sane);
    if (tid == 0) g_flag = (__popcll(m) >= 32) ? 1 : 0;
}

// ---------------- kernel A (fallback): qkv, 1 pt/block
struct QkvSmem { float sf[DP]; float sx[DM]; };

template<int DT>
__device__ __forceinline__ void qkv_body(QkvSmem& s,
    const void* feat, const void* fc1_w, const void* fc1_b,
    const void* wq, const void* wk, const void* wv,
    float* __restrict__ qbuf, float* __restrict__ kbuf, float* __restrict__ vbuf)
{
    const int bn = blockIdx.x;
    const int tid = threadIdx.x;
    if (tid < DP) s.sf[tid] = IO<DT>::ld(feat, (size_t)bn * DP + tid);
    __syncthreads();
    float x = IO<DT>::ld(fc1_b, tid);
#pragma unroll 4
    for (int i = 0; i < DP; i++) x = fmaf(s.sf[i], IO<DT>::ld(fc1_w, i * DM + tid), x);
    s.sx[tid] = x;
    __syncthreads();
    float q = 0.f, k = 0.f, v = 0.f;
    for (int i0 = 0; i0 < DM; i0 += 4) {
        float4 xv = *(const float4*)&s.sx[i0];
        const float xs[4] = { xv.x, xv.y, xv.z, xv.w };
#pragma unroll
        for (int j = 0; j < 4; j++) {
            q = fmaf(xs[j], IO<DT>::ld(wq, (i0 + j) * DM + tid), q);
            k = fmaf(xs[j], IO<DT>::ld(wk, (i0 + j) * DM + tid), k);
            v = fmaf(xs[j], IO<DT>::ld(wv, (i0 + j) * DM + tid), v);
        }
    }
    qbuf[(size_t)bn * DM + tid] = q;
    kbuf[(size_t)bn * DM + tid] = k;
    vbuf[(size_t)bn * DM + tid] = v;
}

__global__ __launch_bounds__(128) void qkv_kernel(
    const void* feat, const void* fc1_w, const void* fc1_b,
    const void* wq, const void* wk, const void* wv,
    float* qbuf, float* kbuf, float* vbuf)
{
    __shared__ __align__(16) QkvSmem s;
    if (g_flag) qkv_body<1>(s, feat, fc1_w, fc1_b, wq, wk, wv, qbuf, kbuf, vbuf);
    else        qkv_body<0>(s, feat, fc1_w, fc1_b, wq, wk, wv, qbuf, kbuf, vbuf);
}

// ---------------- kernel A': qkv, 16 pts/block (proven) ----
struct Qkv16Smem { float sf[16][DP]; float sx[16][DMP]; };

template<int DT>
__device__ __forceinline__ void qkv16_body(Qkv16Smem& s,
    const void* feat, const void* fc1_w, const void* fc1_b,
    const void* wq, const void* wk, const void* wv,
    float* __restrict__ qbuf, float* __restrict__ kbuf, float* __restrict__ vbuf)
{
    const int pnt0 = blockIdx.x << 4;
    const int tid = threadIdx.x;
    {   // stage 16x64 features, one float4 per thread
        const int r = tid >> 4, c4 = (tid & 15) << 2;
        float o[4];
        IO<DT>::ld4(feat, (size_t)(pnt0 + r) * DP + c4, o);
        s.sf[r][c4 + 0] = o[0]; s.sf[r][c4 + 1] = o[1];
        s.sf[r][c4 + 2] = o[2]; s.sf[r][c4 + 3] = o[3];
    }
    __syncthreads();
    const int c = tid & 127, h = tid >> 7;
    {   // X = feat @ fc1_w + fc1_b, 8 points per thread
        float acc[8];
        const float fb = IO<DT>::ld(fc1_b, c);
#pragma unroll
        for (int pp = 0; pp < 8; pp++) acc[pp] = fb;
        for (int i = 0; i < DP; i++) {
            const float w = IO<DT>::ld(fc1_w, (size_t)i * DM + c);
#pragma unroll
            for (int pp = 0; pp < 8; pp++) acc[pp] = fmaf(s.sf[h * 8 + pp][i], w, acc[pp]);
        }
#pragma unroll
        for (int pp = 0; pp < 8; pp++) s.sx[h * 8 + pp][c] = acc[pp];
    }
    __syncthreads();
    {   // q/k/v = X @ W, 8 points per thread, weights loaded once
        float aq[8], ak[8], av[8];
#pragma unroll
        for (int pp = 0; pp < 8; pp++) { aq[pp] = 0.f; ak[pp] = 0.f; av[pp] = 0.f; }
        for (int i0 = 0; i0 < DM; i0 += 4) {
            float x4[8][4];
#pragma unroll
            for (int pp = 0; pp < 8; pp++) {
                const float4 xv = *(const float4*)&s.sx[h * 8 + pp][i0];
                x4[pp][0] = xv.x; x4[pp][1] = xv.y; x4[pp][2] = xv.z; x4[pp][3] = xv.w;
            }
#pragma unroll
            for (int j = 0; j < 4; j++) {
                const float wqv = IO<DT>::ld(wq, (size_t)(i0 + j) * DM + c);
                const float wkv = IO<DT>::ld(wk, (size_t)(i0 + j) * DM + c);
                const float wvv = IO<DT>::ld(wv, (size_t)(i0 + j) * DM + c);
#pragma unroll
                for (int pp = 0; pp < 8; pp++) {
                    aq[pp] = fmaf(x4[pp][j], wqv, aq[pp]);
                    ak[pp] = fmaf(x4[pp][j], wkv, ak[pp]);
                    av[pp] = fmaf(x4[pp][j], wvv, av[pp]);
                }
            }
        }
#pragma unroll
        for (int pp = 0; pp < 8; pp++) {
            const size_t row = (size_t)(pnt0 + h * 8 + pp) * DM + c;
            qbuf[row] = aq[pp]; kbuf[row] = ak[pp]; vbuf[row] = av[pp];
        }
    }
}

__global__ __launch_bounds__(256) void qkv16_kernel(
    const void* feat, const void* fc1_w, const void* fc1_b,
    const void* wq, const void* wk, const void* wv,
    float* qbuf, float* kbuf, float* vbuf)
{
    __shared__ __align__(16) Qkv16Smem s;
    if (g_flag) qkv16_body<1>(s, feat, fc1_w, fc1_b, wq, wk, wv, qbuf, kbuf, vbuf);
    else        qkv16_body<0>(s, feat, fc1_w, fc1_b, wq, wk, wv, qbuf, kbuf, vbuf);
}

// ---------------- kernel B: knn (wave-per-query) -----
template<int DT>
__device__ __forceinline__ void knn_body(float4* __restrict__ sc,
    const void* xyz, int* dst, int dstride, void* dout, int in_out)
{
    if (in_out) {
        if (DT) { dst = (int*)((u16t*)dout + OUT0N); dstride = (KK * DM) / 2; }
        else    { dst = (int*)((float*)dout + OUT0N); dstride = KK * DM; }
    }
    const int b = blockIdx.x >> 9;             // 512 blocks per batch
    const int tid = threadIdx.x;
    for (int j = tid; j < NN; j += 512) {
        float x = IO<DT>::ld(xyz, ((size_t)b * NN + j) * 3 + 0);
        float y = IO<DT>::ld(xyz, ((size_t)b * NN + j) * 3 + 1);
        float z = IO<DT>::ld(xyz, ((size_t)b * NN + j) * 3 + 2);
        float sq = __fadd_rn(__fadd_rn(__fmul_rn(x, x), __fmul_rn(y, y)), __fmul_rn(z, z));
        sc[j] = make_float4(x, y, z, sq);
    }
    __syncthreads();
    const int lane = tid & 63;
    const int wave = tid >> 6;
    const int r = ((blockIdx.x & 511) << 3) + wave;   // query row within batch
    const float4 qc = sc[r];                          // wave-uniform broadcast

    float d[KK];
    int id[KK];
#pragma unroll
    for (int t = 0; t < KK; t++) { d[t] = 3.4e38f; id[t] = 0x7fffffff; }

    for (int j = lane; j < NN; j += 64) {
        const float4 c = sc[j];
        const float dot = __fadd_rn(__fadd_rn(__fmul_rn(qc.x, c.x), __fmul_rn(qc.y, c.y)),
                                    __fmul_rn(qc.z, c.z));
        const float dist = __fsub_rn(__fadd_rn(qc.w, c.w), __fmul_rn(2.0f, dot));
        if (dist < d[KK - 1]) {
            float cd = dist; int ci = j;
#pragma unroll
            for (int t = 0; t < KK; t++) {
                const bool sw = (cd < d[t]);          // strict: stable ties
                const float od = d[t]; const int oi = id[t];
                d[t]  = sw ? cd : d[t];
                id[t] = sw ? ci : id[t];
                cd = sw ? od : cd;
                ci = sw ? oi : ci;
            }
        }
    }

    // wave merge: 16x pop-min over 64 sorted lists
    const size_t base = (size_t)(b * NN + r) * (size_t)dstride;
#pragma unroll
    for (int t = 0; t < KK; t++) {
        float bd = d[0]; int bi = id[0];
#pragma unroll
        for (int off = 32; off >= 1; off >>= 1) {
            const float od = __shfl_xor(bd, off, 64);
            const int   oi = __shfl_xor(bi, off, 64);
            if (od < bd || (od == bd && oi < bi)) { bd = od; bi = oi; }
        }
        const bool win = (d[0] == bd) && (id[0] == bi);   // unique (dist,idx)
        if (win) {
#pragma unroll
            for (int u = 0; u < KK - 1; u++) { d[u] = d[u + 1]; id[u] = id[u + 1]; }
            d[KK - 1] = 3.4e38f; id[KK - 1] = 0x7fffffff;
        }
        if (lane == t) dst[base + t] = bi;
    }
}

__global__ __launch_bounds__(512) void knn_kernel(
    const void* xyz, int* dst, int dstride, void* dout, int in_out)
{
    __shared__ __align__(16) float4 sc[NN];   // 64 KB
    if (g_flag) knn_body<1>(sc, xyz, dst, dstride, dout, in_out);
    else        knn_body<0>(sc, xyz, dst, dstride, dout, in_out);
}

// ---------------- GEMM tile helper (fallback path) ----
template<int DT>
__device__ __forceinline__ void gemm_tile(const float* __restrict__ IN,
                                          const void* __restrict__ W, int woff,
                                          int kg, int f0, float acc[4][4])
{
#pragma unroll
    for (int a = 0; a < 4; a++)
#pragma unroll
        for (int c = 0; c < 4; c++) acc[a][c] = 0.f;
    for (int i0 = 0; i0 < DM; i0 += 4) {
        float w[4][4];
#pragma unroll
        for (int j = 0; j < 4; j++) IO<DT>::ld4(W, (size_t)woff + (i0 + j) * DM + f0, w[j]);
#pragma unroll
        for (int kk = 0; kk < 4; kk++) {
            float4 x4 = *(const float4*)(IN + (kg * 4 + kk) * DMP + i0);
            const float xs[4] = { x4.x, x4.y, x4.z, x4.w };
#pragma unroll
            for (int ff = 0; ff < 4; ff++)
#pragma unroll
                for (int j = 0; j < 4; j++)
                    acc[kk][ff] = fmaf(xs[j], w[j][ff], acc[kk][ff]);
        }
    }
}

// =====================================================
// Weight prep: pack 4 DMxDM matrices (sim_w[1:], d2_w,
// g1_w, g2_w) into MFMA B-fragment order, split fp32 ->
// hi/lo bf16.  Layout per matrix (16384 shorts hi, then
// 16384 shorts lo): frag offset ((tile*4+ks)*64+lane)*8,
// element j = W[ks*32+(lane>>4)*8+j][tile*16+(lane&15)].
// =====================================================
template<int DT>
__device__ __forceinline__ void wprep_body(const void* sim_w, const void* d2_w,
                                           const void* g1_w, const void* g2_w,
                                           u16t* __restrict__ wprep)
{
    const int m  = blockIdx.x >> 3;    // matrix 0..3
    const int t  = blockIdx.x & 7;     // col tile 0..7
    const int ks = threadIdx.x >> 6;   // k-step 0..3
    const int lane = threadIdx.x & 63;
    const void* src = (m == 0) ? sim_w : (m == 1) ? d2_w : (m == 2) ? g1_w : g2_w;
    const int srcoff = (m == 0) ? DM : 0;   // sim_w: skip row 0 (handled in epilogue)
    u16t* hi = wprep + (size_t)m * 32768;
    u16t* lo = hi + 16384;
    const int c  = t * 16 + (lane & 15);
    const int k0 = ks * 32 + ((lane >> 4) << 3);
    s8v vh, vl;
#pragma unroll
    for (int j = 0; j < 8; j++) {
        const float x = IO<DT>::ld(src, (size_t)srcoff + (size_t)(k0 + j) * DM + c);
        const u16t h = f2u(x);
        vh[j] = (short)h;
        vl[j] = (short)f2u(x - u2f(h));
    }
    const size_t off = ((size_t)(t * 4 + ks) * 64 + lane) * 8;
    *(s8v*)(hi + off) = vh;
    *(s8v*)(lo + off) = vl;
}

__global__ __launch_bounds__(256) void wprep_kernel(
    const void* sim_w, const void* d2_w, const void* g1_w, const void* g2_w,
    u16t* wprep)
{
    if (g_flag) wprep_body<1>(sim_w, d2_w, g1_w, g2_w, wprep);
    else        wprep_body<0>(sim_w, d2_w, g1_w, g2_w, wprep);
}

// =====================================================
// 4-point / 4-wave MFMA GEMM core.  Wave w computes
// N-tiles {2w, 2w+1} for ALL 4 M-tiles (points) ->
// block B-fragment loads are disjoint (B traffic /4).
// A from SP (64 rows = pt*16+k, hi/lo planes).
// Layouts (v_mfma_f32_16x16x32_bf16, m89-verified):
//   A: row = lane&15, k = ks*32 + (lane>>4)*8 + j
//   B: col = lane&15, k = ks*32 + (lane>>4)*8 + j
//   D: col = lane&15, row = (lane>>4)*4 + r
// =====================================================
__device__ __forceinline__ void mfma_g(const u16t* __restrict__ SP,
                                       const u16t* __restrict__ wmat,
                                       int lane, int w, f4v acc[4][2])
{
    const u16t* whi = wmat;
    const u16t* wlo = wmat + 16384;
    const int arow = lane & 15;
    const int ak   = (lane >> 4) << 3;
#pragma unroll
    for (int ks = 0; ks < 4; ks++) {
        const size_t o0 = ((size_t)(((2 * w + 0) * 4 + ks) * 64) + lane) * 8;
        const size_t o1 = ((size_t)(((2 * w + 1) * 4 + ks) * 64) + lane) * 8;
        const s8v b0h = *(const s8v*)(whi + o0);
        const s8v b0l = *(const s8v*)(wlo + o0);
        const s8v b1h = *(const s8v*)(whi + o1);
        const s8v b1l = *(const s8v*)(wlo + o1);
#pragma unroll
        for (int m = 0; m < 4; m++) {
            const u16t* ar = SP + (size_t)(m * 16 + arow) * SPITCH + ak + ks * 32;
            const s8v ah = *(const s8v*)ar;
            const s8v al = *(const s8v*)(ar + 128);
            acc[m][0] = __builtin_amdgcn_mfma_f32_16x16x32_bf16(ah, b0h, acc[m][0], 0, 0, 0);
            acc[m][0] = __builtin_amdgcn_mfma_f32_16x16x32_bf16(ah, b0l, acc[m][0], 0, 0, 0);
            acc[m][0] = __builtin_amdgcn_mfma_f32_16x16x32_bf16(al, b0h, acc[m][0], 0, 0, 0);
            acc[m][1] = __builtin_amdgcn_mfma_f32_16x16x32_bf16(ah, b1h, acc[m][1], 0, 0, 0);
            acc[m][1] = __builtin_amdgcn_mfma_f32_16x16x32_bf16(ah, b1l, acc[m][1], 0, 0, 0);
            acc[m][1] = __builtin_amdgcn_mfma_f32_16x16x32_bf16(al, b1h, acc[m][1], 0, 0, 0);
        }
    }
}

// ---------------- kernel C: MFMA attn, 4 pts / 4 waves
// Lean LDS (~38 KB) -> 4 blocks/CU, 16 waves/CU.
// rel_qk and pos_enc live in D-layout REGISTERS; the only
// LDS tile is the split A-operand SP (reused as V stage).
struct Attn4Smem {
    u16t  SP[64 * SPITCH];   // 33792 B; aliased as float[64][132] for V stage
    float sq[4][DM];         // 2048
    float sres[4][DM];       // 2048
    float ssim[64];          // 256
    float srp[64][3];        // 768
    int   sidx[64];          // 256
};

template<int DT>
__device__ __forceinline__ void attn4w_body(Attn4Smem& s,
    const void* xyz, const void* feat,
    const void* fc2_w, const void* fc2_b,
    const void* d1_w, const void* d1_b, const void* d2_b,
    const void* g1_b, const void* g2_b,
    const void* sim_w, const void* sim_b,
    const float* __restrict__ qbuf, const float* __restrict__ kbuf,
    const float* __restrict__ vbuf,
    const int* __restrict__ knn, const u16t* __restrict__ wprep, void* dout)
{
    void* out0 = dout;
    void* out1 = DT ? (void*)((u16t*)dout + OUT0N) : (void*)((float*)dout + OUT0N);
    const int pnt0 = blockIdx.x << 2;
    const int b = pnt0 >> 12;
    const int tid = threadIdx.x;
    const int lane = tid & 63;
    const int w = tid >> 6;          // wave = N-tile pair owner
    const int h = lane >> 4;         // D-row group
    const int c = lane & 15;         // D-col within tile

    // ---- Ph0: indices, rel_pos, q staging, |q| ----
    if (tid < 64) {
        int sv = knn[(size_t)(pnt0 + (tid >> 4)) * KK + (tid & 15)];
        sv = (sv < 0) ? 0 : (sv > NN - 1 ? NN - 1 : sv);
        s.sidx[tid] = sv;
        const int pt = tid >> 4;
        const int grow = (b << 12) + sv;
#pragma unroll
        for (int c3 = 0; c3 < 3; c3++)
            s.srp[tid][c3] = IO<DT>::ld(xyz, (size_t)(pnt0 + pt) * 3 + c3)
                           - IO<DT>::ld(xyz, (size_t)grow * 3 + c3);
    }
    const float2 q2 = *(const float2*)&qbuf[(size_t)(pnt0 + w) * DM + lane * 2];
    *(float2*)&s.sq[w][lane * 2] = q2;
    float qq = fmaf(q2.x, q2.x, q2.y * q2.y);
#pragma unroll
    for (int off = 1; off <= 32; off <<= 1) qq += __shfl_xor(qq, off, 64);
    const float qn = fmaxf(sqrtf(qq), EPSF);   // wave-uniform: |q| of point w
    __syncthreads();   // B1

    // ---- Ph1: SP = split(relu(rel_pos @ d1_w + d1_b)) ----
    {
        const int row = tid >> 2, cb = (tid & 3) << 5;
        const float rx = s.srp[row][0], ry = s.srp[row][1], rz = s.srp[row][2];
        u16t* hp = &s.SP[row * SPITCH];
#pragma unroll
        for (int j4 = 0; j4 < 32; j4 += 4) {
            float w0[4], w1[4], w2[4], bb[4];
            IO<DT>::ld4(d1_w, (size_t)0 * DM + cb + j4, w0);
            IO<DT>::ld4(d1_w, (size_t)1 * DM + cb + j4, w1);
            IO<DT>::ld4(d1_w, (size_t)2 * DM + cb + j4, w2);
            IO<DT>::ld4(d1_b, cb + j4, bb);
            ushort4 hv, lv;
#pragma unroll
            for (int jj = 0; jj < 4; jj++) {
                const float hx = fmaxf(fmaf(rz, w2[jj], fmaf(ry, w1[jj], fmaf(rx, w0[jj], bb[jj]))), 0.f);
                u16t hs, ls; splitf(hx, hs, ls);
                ((u16t*)&hv)[jj] = hs; ((u16t*)&lv)[jj] = ls;
            }
            *(ushort4*)(hp + cb + j4) = hv;
            *(ushort4*)(hp + 128 + cb + j4) = lv;
        }
    }
    __syncthreads();   // B2

    // ---- Ph2: GEMM2 -> PE regs (pos_enc incl d2_b) ----
    f4v pe[4][2] = { { {0,0,0,0},{0,0,0,0} }, { {0,0,0,0},{0,0,0,0} },
                     { {0,0,0,0},{0,0,0,0} }, { {0,0,0,0},{0,0,0,0} } };
    mfma_g(s.SP, wprep + 1 * 32768, lane, w, pe);
#pragma unroll
    for (int nt = 0; nt < 2; nt++) {
        const float bv = IO<DT>::ld(d2_b, (2 * w + nt) * 16 + c);
#pragma unroll
        for (int m = 0; m < 4; m++)
#pragma unroll
            for (int r = 0; r < 4; r++) pe[m][nt][r] += bv;
    }
    __syncthreads();   // B3 (all waves' GEMM2 A-reads done)

    // ---- Ph3: gather K; SP = split(q - K); norms -> ssim ----
    {
        const int row = tid >> 2, cb = (tid & 3) << 5;
        const int pt = row >> 4;   // == w
        const int grow = (b << 12) + s.sidx[row];
        const float* krow = &kbuf[(size_t)grow * DM];
        u16t* hp = &s.SP[row * SPITCH];
        float sk = 0.f, sd = 0.f;
#pragma unroll
        for (int j4 = 0; j4 < 32; j4 += 4) {
            const float4 kv = *(const float4*)&krow[cb + j4];
            const float4 qv = *(const float4*)&s.sq[pt][cb + j4];
            ushort4 hv, lv;
            splitf(qv.x - kv.x, hv.x, lv.x);
            splitf(qv.y - kv.y, hv.y, lv.y);
            splitf(qv.z - kv.z, hv.z, lv.z);
            splitf(qv.w - kv.w, hv.w, lv.w);
            *(ushort4*)(hp + cb + j4) = hv;
            *(ushort4*)(hp + 128 + cb + j4) = lv;
            sk = fmaf(kv.x, kv.x, fmaf(kv.y, kv.y, fmaf(kv.z, kv.z, fmaf(kv.w, kv.w, sk))));
            sd = fmaf(qv.x, kv.x, fmaf(qv.y, kv.y, fmaf(qv.z, kv.z, fmaf(qv.w, kv.w, sd))));
        }
        sk += __shfl_xor(sk, 1, 64); sk += __shfl_xor(sk, 2, 64);
        sd += __shfl_xor(sd, 1, 64); sd += __shfl_xor(sd, 2, 64);
        if ((tid & 3) == 0) {
            const float kn = fmaxf(sqrtf(sk), EPSF);
            s.ssim[row] = sd / (qn * kn);
        }
    }
    __syncthreads();   // B4

    // ---- Ph4: GEMM1 -> fused (rel_qk + pos_enc) -> SP ----
    {
        f4v a1[4][2] = { { {0,0,0,0},{0,0,0,0} }, { {0,0,0,0},{0,0,0,0} },
                         { {0,0,0,0},{0,0,0,0} }, { {0,0,0,0},{0,0,0,0} } };
        mfma_g(s.SP, wprep + 0 * 32768, lane, w, a1);
        __syncthreads();   // B5 (all A-reads done before overwrite)
#pragma unroll
        for (int nt = 0; nt < 2; nt++) {
            const int col = (2 * w + nt) * 16 + c;
            const float bv  = IO<DT>::ld(sim_b, col);
            const float w0v = IO<DT>::ld(sim_w, col);
#pragma unroll
            for (int m = 0; m < 4; m++)
#pragma unroll
                for (int r = 0; r < 4; r++) {
                    const int row = m * 16 + 4 * h + r;
                    const float val = a1[m][nt][r] + bv + s.ssim[row] * w0v + pe[m][nt][r];
                    u16t hs, ls; splitf(val, hs, ls);
                    s.SP[(size_t)row * SPITCH + col] = hs;
                    s.SP[(size_t)row * SPITCH + 128 + col] = ls;
                }
        }
    }
    __syncthreads();   // B6

    // ---- Ph5: GEMM3 -> relu -> SP ----
    {
        f4v a3[4][2] = { { {0,0,0,0},{0,0,0,0} }, { {0,0,0,0},{0,0,0,0} },
                         { {0,0,0,0},{0,0,0,0} }, { {0,0,0,0},{0,0,0,0} } };
        mfma_g(s.SP, wprep + 2 * 32768, lane, w, a3);
        __syncthreads();   // B7
#pragma unroll
        for (int nt = 0; nt < 2; nt++) {
            const int col = (2 * w + nt) * 16 + c;
            const float bv = IO<DT>::ld(g1_b, col);
#pragma unroll
            for (int m = 0; m < 4; m++)
#pragma unroll
                for (int r = 0; r < 4; r++) {
                    const int row = m * 16 + 4 * h + r;
                    const float val = fmaxf(a3[m][nt][r] + bv, 0.f);
                    u16t hs, ls; splitf(val, hs, ls);
                    s.SP[(size_t)row * SPITCH + col] = hs;
                    s.SP[(size_t)row * SPITCH + 128 + col] = ls;
                }
        }
    }
    __syncthreads();   // B8

    // ---- Ph6: GEMM4 -> softmax (in-register, 4-lane groups) -> out1 ----
    f4v av[4][2];
    {
        f4v a4[4][2] = { { {0,0,0,0},{0,0,0,0} }, { {0,0,0,0},{0,0,0,0} },
                         { {0,0,0,0},{0,0,0,0} }, { {0,0,0,0},{0,0,0,0} } };
        mfma_g(s.SP, wprep + 3 * 32768, lane, w, a4);
        const float inv = 0.08838834764831843f;   // 1/sqrt(128)
#pragma unroll
        for (int nt = 0; nt < 2; nt++) {
            const int col = (2 * w + nt) * 16 + c;
            const float bv = IO<DT>::ld(g2_b, col);
#pragma unroll
            for (int m = 0; m < 4; m++) {
                float tv[4];
#pragma unroll
                for (int r = 0; r < 4; r++) tv[r] = (a4[m][nt][r] + bv) * inv;
                float mx = fmaxf(fmaxf(tv[0], tv[1]), fmaxf(tv[2], tv[3]));
                mx = fmaxf(mx, __shfl_xor(mx, 16, 64));
                mx = fmaxf(mx, __shfl_xor(mx, 32, 64));
                float ssum = 0.f;
#pragma unroll
                for (int r = 0; r < 4; r++) { tv[r] = __expf(tv[r] - mx); ssum += tv[r]; }
                ssum += __shfl_xor(ssum, 16, 64);
                ssum += __shfl_xor(ssum, 32, 64);
                const float rs = 1.0f / ssum;
#pragma unroll
                for (int r = 0; r < 4; r++) {
                    const float a = tv[r] * rs;
                    av[m][nt][r] = a;
                    IO<DT>::st(out1, ((size_t)(pnt0 + m) * KK + (4 * h + r)) * DM + col, a);
                }
            }
        }
    }
    __syncthreads();   // B9 (all GEMM4 A-reads done; SP free)

    // ---- Ph7: stage V into vst (= SP alias); einsum -> sres ----
    float* vst = (float*)s.SP;   // [64][132] = 33792 B, exactly SP
    {
        const int row = tid >> 2, cb = (tid & 3) << 5;
        const int grow = (b << 12) + s.sidx[row];
        const float* vrow = &vbuf[(size_t)grow * DM];
#pragma unroll
        for (int j4 = 0; j4 < 32; j4 += 4)
            *(float4*)&vst[row * 132 + cb + j4] = *(const float4*)&vrow[cb + j4];
    }
    __syncthreads();   // B10
    {
#pragma unroll
        for (int nt = 0; nt < 2; nt++) {
            const int col = (2 * w + nt) * 16 + c;
#pragma unroll
            for (int m = 0; m < 4; m++) {
                float part = 0.f;
#pragma unroll
                for (int r = 0; r < 4; r++)
                    part = fmaf(av[m][nt][r],
                                vst[(m * 16 + 4 * h + r) * 132 + col] + pe[m][nt][r], part);
                part += __shfl_xor(part, 16, 64);
                part += __shfl_xor(part, 32, 64);
                if (h == 0) s.sres[m][col] = part;
            }
        }
    }
    __syncthreads();   // B11

    // ---- Ph8: out0 = res @ fc2_w + fc2_b + features ----
    {
        const int pt = tid >> 6, cc = tid & 63;
        float o = 0.f;
        for (int i = 0; i < DM; i++)
            o = fmaf(s.sres[pt][i], IO<DT>::ld(fc2_w, (size_t)i * DP + cc), o);
        o = o + IO<DT>::ld(fc2_b, cc) + IO<DT>::ld(feat, (size_t)(pnt0 + pt) * DP + cc);
        IO<DT>::st(out0, (size_t)(pnt0 + pt) * DP + cc, o);
    }
}

__global__ __launch_bounds__(256, 4) void attn4w_kernel(
    const void* xyz, const void* feat,
    const void* fc2_w, const void* fc2_b,
    const void* d1_w, const void* d1_b, const void* d2_b,
    const void* g1_b, const void* g2_b,
    const void* sim_w, const void* sim_b,
    const float* qbuf, const float* kbuf, const float* vbuf,
    const int* knn, const u16t* wprep, void* dout)
{
    __shared__ __align__(16) Attn4Smem s;
    if (g_flag)
        attn4w_body<1>(s, xyz, feat, fc2_w, fc2_b, d1_w, d1_b, d2_b, g1_b, g2_b,
                       sim_w, sim_b, qbuf, kbuf, vbuf, knn, wprep, dout);
    else
        attn4w_body<0>(s, xyz, feat, fc2_w, fc2_b, d1_w, d1_b, d2_b, g1_b, g2_b,
                       sim_w, sim_b, qbuf, kbuf, vbuf, knn, wprep, dout);
}

// ---------------- kernel C: attn (fallback paths) ----
template<bool FUSED> struct AttnSmem {
    float Kb[KK * DMP], Vb[KK * DMP], PE[KK * DMP], T0[KK * DMP], T1[KK * DMP];
    float s_q[DM], sres[DM];
    float SF[FUSED ? 17 * DP : 1];
    float X[FUSED ? 17 * DMP : 1];
    float srp[KK][3];
    float ssim[KK], skn[KK], sdot[KK];
    float sqn;
    int sidx[KK];
};

template<int DT, bool FUSED>
__device__ __forceinline__ void attn_body(AttnSmem<FUSED>& s,
    const void* xyz, const void* feat,
    const void* fc1_w, const void* fc1_b, const void* fc2_w, const void* fc2_b,
    const void* d1_w, const void* d1_b, const void* d2_w, const void* d2_b,
    const void* g1_w, const void* g1_b, const void* g2_w, const void* g2_b,
    const void* sim_w, const void* sim_b,
    const void* wq, const void* wk, const void* wv,
    const float* __restrict__ qbuf, const float* __restrict__ kbuf, const float* __restrict__ vbuf,
    const int* knn, int knn_stride, int knn_in_out, void* dout)
{
    void* out0 = dout;
    void* out1 = DT ? (void*)((u16t*)dout + OUT0N) : (void*)((float*)dout + OUT0N);
    if (knn_in_out) {
        if (DT) { knn = (const int*)((const u16t*)dout + OUT0N); knn_stride = (KK * DM) / 2; }
        else    { knn = (const int*)((const float*)dout + OUT0N); knn_stride = KK * DM; }
    }

    const int bn = blockIdx.x;
    const int b = bn >> 12;
    const int tid = threadIdx.x;
    const int f = tid;
    const int f0 = (tid & 31) * 4;
    const int kg = tid >> 5;

    if (tid < KK) {
        int sv = knn[(size_t)bn * knn_stride + tid];
        sv = (sv < 0) ? 0 : (sv > NN - 1 ? NN - 1 : sv);   // defensive, never OOB
        s.sidx[tid] = sv;
    }
    __syncthreads();

    if constexpr (FUSED) {
        for (int idx = tid; idx < 17 * DP; idx += 128) {
            const int r = idx >> 6, c = idx & 63;
            const int row = (r < KK) ? ((b << 12) + s.sidx[r]) : bn;
            s.SF[idx] = IO<DT>::ld(feat, (size_t)row * DP + c);
        }
        __syncthreads();
        float xacc[17];
        const float fb = IO<DT>::ld(fc1_b, tid);
#pragma unroll
        for (int r = 0; r < 17; r++) xacc[r] = fb;
        for (int i = 0; i < DP; i++) {
            const float w = IO<DT>::ld(fc1_w, i * DM + tid);
#pragma unroll
            for (int r = 0; r < 17; r++) xacc[r] = fmaf(s.SF[r * DP + i], w, xacc[r]);
        }
#pragma unroll
        for (int r = 0; r < 17; r++) s.X[r * DMP + tid] = xacc[r];
        __syncthreads();
        {
            float a2[4][4];
            gemm_tile<DT>(s.X, wk, 0, kg, f0, a2);
#pragma unroll
            for (int kk = 0; kk < 4; kk++)
                *(float4*)&s.Kb[(kg * 4 + kk) * DMP + f0] =
                    make_float4(a2[kk][0], a2[kk][1], a2[kk][2], a2[kk][3]);
            gemm_tile<DT>(s.X, wv, 0, kg, f0, a2);
#pragma unroll
            for (int kk = 0; kk < 4; kk++)
                *(float4*)&s.Vb[(kg * 4 + kk) * DMP + f0] =
                    make_float4(a2[kk][0], a2[kk][1], a2[kk][2], a2[kk][3]);
        }
        {
            float qv = 0.f;
            for (int i0 = 0; i0 < DM; i0 += 4) {
                float4 x4 = *(const float4*)&s.X[16 * DMP + i0];
                const float xs[4] = { x4.x, x4.y, x4.z, x4.w };
#pragma unroll
                for (int j = 0; j < 4; j++)
                    qv = fmaf(xs[j], IO<DT>::ld(wq, (i0 + j) * DM + tid), qv);
            }
            s.s_q[tid] = qv;
        }
    } else {
        s.s_q[f] = qbuf[(size_t)bn * DM + f];
#pragma unroll
        for (int k = 0; k < KK; k++) {
            const int row = (b << 12) + s.sidx[k];
            s.Kb[k * DMP + f] = kbuf[(size_t)row * DM + f];
            s.Vb[k * DMP + f] = vbuf[(size_t)row * DM + f];
        }
    }
    if (tid < KK) {
        const int row = (b << 12) + s.sidx[tid];
#pragma unroll
        for (int c = 0; c < 3; c++)
            s.srp[tid][c] = IO<DT>::ld(xyz, (size_t)bn * 3 + c) - IO<DT>::ld(xyz, (size_t)row * 3 + c);
    }
    __syncthreads();

    // norms + q.k dots
    if (tid < KK) {
        float sk = 0.f, sd = 0.f;
        for (int i = 0; i < DM; i++) {
            float v2 = s.Kb[tid * DMP + i];
            sk = fmaf(v2, v2, sk);
            sd = fmaf(s.s_q[i], v2, sd);
        }
        s.skn[tid] = fmaxf(sqrtf(sk), EPSF);
        s.sdot[tid] = sd;
    } else if (tid == KK) {
        float sqq = 0.f;
        for (int i = 0; i < DM; i++) { float v2 = s.s_q[i]; sqq = fmaf(v2, v2, sqq); }
        s.sqn = fmaxf(sqrtf(sqq), EPSF);
    }
    __syncthreads();
    if (tid < KK) s.ssim[tid] = s.sdot[tid] / (s.sqn * s.skn[tid]);
#pragma unroll
    for (int k = 0; k < KK; k++) s.T0[k * DMP + f] = s.s_q[f] - s.Kb[k * DMP + f];
    __syncthreads();

    float acc[4][4];

    // rel_qk = [sim, q-k] @ sim_w + sim_b  -> T1
    gemm_tile<DT>(s.T0, sim_w, DM, kg, f0, acc);
    {
        float w0f[4], sbf[4];
        IO<DT>::ld4(sim_w, f0, w0f);
        IO<DT>::ld4(sim_b, f0, sbf);
#pragma unroll
        for (int kk = 0; kk < 4; kk++) {
            float sm = s.ssim[kg * 4 + kk];
            float4 o;
            o.x = fmaf(sm, w0f[0], acc[kk][0]) + sbf[0];
            o.y = fmaf(sm, w0f[1], acc[kk][1]) + sbf[1];
            o.z = fmaf(sm, w0f[2], acc[kk][2]) + sbf[2];
            o.w = fmaf(sm, w0f[3], acc[kk][3]) + sbf[3];
            *(float4*)&s.T1[(kg * 4 + kk) * DMP + f0] = o;
        }
    }
    __syncthreads();

    // h = relu(rel_pos @ d1_w + d1_b) -> T0
    {
        float w0 = IO<DT>::ld(d1_w, 0 * DM + f), w1 = IO<DT>::ld(d1_w, 1 * DM + f),
              w2 = IO<DT>::ld(d1_w, 2 * DM + f);
        float hb = IO<DT>::ld(d1_b, f);
#pragma unroll
        for (int k = 0; k < KK; k++) {
            float h = fmaf(s.srp[k][2], w2, fmaf(s.srp[k][1], w1, fmaf(s.srp[k][0], w0, hb)));
            s.T0[k * DMP + f] = fmaxf(h, 0.f);
        }
    }
    __syncthreads();

    // pos_enc = h @ d2_w + d2_b -> PE
    gemm_tile<DT>(s.T0, d2_w, 0, kg, f0, acc);
    {
        float bf[4];
        IO<DT>::ld4(d2_b, f0, bf);
#pragma unroll
        for (int kk = 0; kk < 4; kk++)
            *(float4*)&s.PE[(kg * 4 + kk) * DMP + f0] =
                make_float4(acc[kk][0] + bf[0], acc[kk][1] + bf[1],
                            acc[kk][2] + bf[2], acc[kk][3] + bf[3]);
    }
    __syncthreads();

    // T0 = T1 + PE
#pragma unroll
    for (int kk = 0; kk < 4; kk++) {
        const int row = (kg * 4 + kk) * DMP + f0;
        float4 a4 = *(const float4*)&s.T1[row];
        float4 p4 = *(const float4*)&s.PE[row];
        *(float4*)&s.T0[row] = make_float4(a4.x + p4.x, a4.y + p4.y, a4.z + p4.z, a4.w + p4.w);
    }
    __syncthreads();

    // T1 = relu(T0 @ g1_w + g1_b)
    gemm_tile<DT>(s.T0, g1_w, 0, kg, f0, acc);
    {
        float bf[4];
        IO<DT>::ld4(g1_b, f0, bf);
#pragma unroll
        for (int kk = 0; kk < 4; kk++)
            *(float4*)&s.T1[(kg * 4 + kk) * DMP + f0] =
                make_float4(fmaxf(acc[kk][0] + bf[0], 0.f), fmaxf(acc[kk][1] + bf[1], 0.f),
                            fmaxf(acc[kk][2] + bf[2], 0.f), fmaxf(acc[kk][3] + bf[3], 0.f));
    }
    __syncthreads();

    // T0 = T1 @ g2_w + g2_b
    gemm_tile<DT>(s.T1, g2_w, 0, kg, f0, acc);
    {
        float bf[4];
        IO<DT>::ld4(g2_b, f0, bf);
#pragma unroll
        for (int kk = 0; kk < 4; kk++)
            *(float4*)&s.T0[(kg * 4 + kk) * DMP + f0] =
                make_float4(acc[kk][0] + bf[0], acc[kk][1] + bf[1],
                            acc[kk][2] + bf[2], acc[kk][3] + bf[3]);
    }
    __syncthreads();

    // softmax over K + einsum
    {
        const float sq128 = 11.31370849898476f;
        float tv[KK];
        float m = -3.4e38f;
#pragma unroll
        for (int k = 0; k < KK; k++) { tv[k] = s.T0[k * DMP + f] / sq128; m = fmaxf(m, tv[k]); }
        float ssum = 0.f;
#pragma unroll
        for (int k = 0; k < KK; k++) { tv[k] = expf(tv[k] - m); ssum += tv[k]; }
        float rf = 0.f;
#pragma unroll
        for (int k = 0; k < KK; k++) {
            float a = tv[k] / ssum;
            IO<DT>::st(out1, ((size_t)bn * KK + k) * DM + f, a);
            rf = fmaf(a, s.Vb[k * DMP + f] + s.PE[k * DMP + f], rf);
        }
        s.sres[f] = rf;
    }
    __syncthreads();

    // out0 = res @ fc2_w + fc2_b + features
    if (tid < DP) {
        float o = 0.f;
        for (int i = 0; i < DM; i++) o = fmaf(s.sres[i], IO<DT>::ld(fc2_w, i * DP + tid), o);
        o = o + IO<DT>::ld(fc2_b, tid) + IO<DT>::ld(feat, (size_t)bn * DP + tid);
        IO<DT>::st(out0, (size_t)bn * DP + tid, o);
    }
}

template<bool FUSED>
__global__ __launch_bounds__(128) void attn_kernel(
    const void* xyz, const void* feat,
    const void* fc1_w, const void* fc1_b, const void* fc2_w, const void* fc2_b,
    const void* d1_w, const void* d1_b, const void* d2_w, const void* d2_b,
    const void* g1_w, const void* g1_b, const void* g2_w, const void* g2_b,
    const void* sim_w, const void* sim_b,
    const void* wq, const void* wk, const void* wv,
    const float* qbuf, const float* kbuf, const float* vbuf,
    const int* knn, int knn_stride, int knn_in_out, void* dout)
{
    __shared__ __align__(16) AttnSmem<FUSED> s;
    if (g_flag)
        attn_body<1, FUSED>(s, xyz, feat, fc1_w, fc1_b, fc2_w, fc2_b, d1_w, d1_b, d2_w, d2_b,
                            g1_w, g1_b, g2_w, g2_b, sim_w, sim_b, wq, wk, wv,
                            qbuf, kbuf, vbuf, knn, knn_stride, knn_in_out, dout);
    else
        attn_body<0, FUSED>(s, xyz, feat, fc1_w, fc1_b, fc2_w, fc2_b, d1_w, d1_b, d2_w, d2_b,
                            g1_w, g1_b, g2_w, g2_b, sim_w, sim_b, wq, wk, wv,
                            qbuf, kbuf, vbuf, knn, knn_stride, knn_in_out, dout);
}

// ---------------------------------------------------------------- launch
extern "C" void kernel_launch(void* const* d_in, const int* in_sizes, int n_in,
                              void* d_out, int out_size, void* d_ws, size_t ws_size,
                              hipStream_t stream)
{
    const void* xyz   = d_in[0];
    const void* feat  = d_in[1];
    const void* fc1_w = d_in[2];
    const void* fc1_b = d_in[3];
    const void* fc2_w = d_in[4];
    const void* fc2_b = d_in[5];
    const void* d1_w  = d_in[6];
    const void* d1_b  = d_in[7];
    const void* d2_w  = d_in[8];
    const void* d2_b  = d_in[9];
    const void* g1_w  = d_in[10];
    const void* g1_b  = d_in[11];
    const void* g2_w  = d_in[12];
    const void* g2_b  = d_in[13];
    const void* wq_w  = d_in[14];
    const void* wk_w  = d_in[15];
    const void* wv_w  = d_in[16];
    const void* sim_w = d_in[17];
    const void* sim_b = d_in[18];

    detect_kernel<<<1, 64, 0, stream>>>(feat);

    const size_t need_qkv = (size_t)3 * BB * NN * DM * sizeof(float);
    const size_t need_knn = (size_t)BB * NN * KK * sizeof(int);
    const size_t need_wp  = (size_t)4 * 2 * 16384 * sizeof(u16t);   // 256 KB packed weights

    if (ws_size >= need_qkv + need_knn + need_wp && d_ws != nullptr) {
        float* qbuf  = (float*)d_ws;
        float* kbuf  = qbuf + (size_t)BB * NN * DM;
        float* vbuf  = kbuf + (size_t)BB * NN * DM;
        int*   knn   = (int*)(vbuf + (size_t)BB * NN * DM);
        u16t*  wprep = (u16t*)(knn + (size_t)BB * NN * KK);
        qkv16_kernel<<<(BB * NN) / 16, 256, 0, stream>>>(feat, fc1_w, fc1_b, wq_w, wk_w, wv_w,
                                                         qbuf, kbuf, vbuf);
        knn_kernel<<<BB * 512, 512, 0, stream>>>(xyz, knn, KK, d_out, 0);
        wprep_kernel<<<32, 256, 0, stream>>>(sim_w, d2_w, g1_w, g2_w, wprep);
        attn4w_kernel<<<(BB * NN) / 4, 256, 0, stream>>>(
            xyz, feat, fc2_w, fc2_b, d1_w, d1_b, d2_b, g1_b, g2_b, sim_w, sim_b,
            qbuf, kbuf, vbuf, knn, wprep, d_out);
    } else if (ws_size >= need_qkv + need_knn && d_ws != nullptr) {
        float* qbuf = (float*)d_ws;
        float* kbuf = qbuf + (size_t)BB * NN * DM;
        float* vbuf = kbuf + (size_t)BB * NN * DM;
        int*   knn  = (int*)(vbuf + (size_t)BB * NN * DM);
        qkv_kernel<<<BB * NN, DM, 0, stream>>>(feat, fc1_w, fc1_b, wq_w, wk_w, wv_w, qbuf, kbuf, vbuf);
        knn_kernel<<<BB * 512, 512, 0, stream>>>(xyz, knn, KK, d_out, 0);
        attn_kernel<false><<<BB * NN, DM, 0, stream>>>(
            xyz, feat, fc1_w, fc1_b, fc2_w, fc2_b, d1_w, d1_b, d2_w, d2_b,
            g1_w, g1_b, g2_w, g2_b, sim_w, sim_b, wq_w, wk_w, wv_w,
            qbuf, kbuf, vbuf, knn, KK, 0, d_out);
    } else if (ws_size >= need_knn && d_ws != nullptr) {
        int* knn = (int*)d_ws;
        knn_kernel<<<BB * 512, 512, 0, stream>>>(xyz, knn, KK, d_out, 0);
        attn_kernel<true><<<BB * NN, DM, 0, stream>>>(
            xyz, feat, fc1_w, fc1_b, fc2_w, fc2_b, d1_w, d1_b, d2_w, d2_b,
            g1_w, g1_b, g2_w, g2_b, sim_w, sim_b, wq_w, wk_w, wv_w,
            nullptr, nullptr, nullptr, knn, KK, 0, d_out);
    } else {
        knn_kernel<<<BB * 512, 512, 0, stream>>>(xyz, nullptr, 0, d_out, 1);
        attn_kernel<true><<<BB * NN, DM, 0, stream>>>(
            xyz, feat, fc1_w, fc1_b, fc2_w, fc2_b, d1_w, d1_b, d2_w, d2_b,
            g1_w, g1_b, g2_w, g2_b, sim_w, sim_b, wq_w, wk_w, wv_w,
            nullptr, nullptr, nullptr, nullptr, 0, 1, d_out);
    }
}